// Round 19
// baseline (392.485 us; speedup 1.0000x reference)
//
#include <hip/hip_runtime.h>

#define HH   128
#define H2   256
#define H3   384
#define NPT  65535      // nodes per tree (2^16 - 1)
#define TPB  512

typedef __bf16    bf16x8 __attribute__((ext_vector_type(8)));
typedef float     f32x4  __attribute__((ext_vector_type(4)));
typedef _Float16  f16x4  __attribute__((ext_vector_type(4)));
typedef _Float16  half_t;

__device__ unsigned short Wb_g[640 * 256];   // bf16 [row=output col j][k]; j<384: W_iou, else W_f

__device__ __forceinline__ float fsig(float x)  { return 1.0f / (1.0f + __expf(-x)); }
__device__ __forceinline__ float ftanh(float x) { return 1.0f - 2.0f / (__expf(2.0f * x) + 1.0f); }
__device__ __forceinline__ unsigned short f2bf(float f) {   // RNE fp32->bf16
    unsigned u = __float_as_uint(f);
    u += 0x7fffu + ((u >> 16) & 1u);
    return (unsigned short)(u >> 16);
}
__device__ __forceinline__ int swz(int off) { return off ^ (((off >> 9) & 7) << 4); }

// ---------------- weight convert ----------------
__global__ __launch_bounds__(256) void conv_k(const float* __restrict__ W_iou,
                                              const float* __restrict__ W_f)
{
    int t    = blockIdx.x * 256 + threadIdx.x;
    int base = t * 4;
    int j = base >> 8, k = base & 255;
    const float* src = (j < H3) ? (W_iou + j * H2 + k)
                                : (W_f + (j - H3) * H2 + k);
    float4 v = *(const float4*)src;
    ushort4 p;
    p.x = f2bf(v.x); p.y = f2bf(v.y); p.z = f2bf(v.z); p.w = f2bf(v.w);
    *(ushort4*)(Wb_g + base) = p;
}

#define GATES5(PI, PO, PU, PL, PR, CL, CR, HV, CV) \
    { CV = fsig(PI) * ftanh(PU) + fsig(PL) * (CL) + fsig(PR) * (CR); \
      HV = fsig(PO) * ftanh(CV); }

// ---------------- fused leaf + l=14: 256 threads, 16-node tile, 8 blocks/CU target ----------------
// Block b owns l=14 nodes [16b,16b+16) and their 32 leaf children. Leaf phase:
// gates elementwise, h -> h_g (nontemporal) + swizzled LDS A-tile (bf16), c -> LDS.
// l=14 phase: 16x16 MFMA, wave w owns col-groups {w*16+lr, 64+w*16+lr} x 5 gates.
// iou is read-once -> nontemporal loads (preserve L2/L3 for h_bf/c_ws reuse).
__global__ __launch_bounds__(256, 4) void leaf14_k(
    const float* __restrict__ iou, const float* __restrict__ c_in,
    const float* __restrict__ b_iou, const float* __restrict__ b_f,
    float* __restrict__ h_g, half_t* __restrict__ c_ws,
    unsigned short* __restrict__ h_bf)
{
    __shared__ __align__(16) unsigned short A_lds[16 * H2];   // 8 KB: h of 32 leaves, A-layout
    __shared__ __align__(16) half_t         C_lds[32 * HH];   // 8 KB: c of 32 leaves

    const int tid = threadIdx.x;
    const int w  = tid >> 6;            // wave 0..3
    const int lr = tid & 15;
    const int lc = (tid & 63) >> 4;
    const int node0 = blockIdx.x * 16;                            // l=14 tile base
    const int tree  = node0 >> 14;
    const int lbase = tree * NPT + 32767 + 2 * (node0 & 16383);   // first of 32 leaf rows

    // ---- leaf phase: 1024 float4-items over [32 rows][32 float4] ----
#pragma unroll
    for (int it = 0; it < 4; ++it) {
        int p   = tid + 256 * it;
        int row = p >> 5;            // 0..31
        int e4  = p & 31;
        int grow = lbase + row;
        const float* ip = iou + (size_t)grow * H3 + e4 * 4;
        f32x4 vi = __builtin_nontemporal_load((const f32x4*)(ip));
        f32x4 vo = __builtin_nontemporal_load((const f32x4*)(ip + HH));
        f32x4 vu = __builtin_nontemporal_load((const f32x4*)(ip + 2 * HH));
        f32x4 vc = __builtin_nontemporal_load((const f32x4*)(c_in + (size_t)grow * HH + e4 * 4));
        float4 bi4 = *(const float4*)(b_iou + e4 * 4);
        float4 bo4 = *(const float4*)(b_iou + HH + e4 * 4);
        float4 bu4 = *(const float4*)(b_iou + 2 * HH + e4 * 4);

        f32x4 hn, cn;
#define DOL(X) { float iv = fsig(vi.X + bi4.X); float ov = fsig(vo.X + bo4.X); \
                 float uv = ftanh(vu.X + bu4.X); float cv = iv * uv + vc.X;    \
                 cn.X = cv; hn.X = ov * ftanh(cv); }
        DOL(x) DOL(y) DOL(z) DOL(w)
#undef DOL
        __builtin_nontemporal_store(hn, (f32x4*)(h_g + (size_t)grow * HH + e4 * 4));
        f16x4 cf; cf.x = (half_t)cn.x; cf.y = (half_t)cn.y;
        cf.z = (half_t)cn.z; cf.w = (half_t)cn.w;
        *(f16x4*)(C_lds + row * HH + e4 * 4) = cf;
        int m = row >> 1, half = row & 1;
        uint2 pk;
        pk.x = (unsigned)f2bf(hn.x) | ((unsigned)f2bf(hn.y) << 16);
        pk.y = (unsigned)f2bf(hn.z) | ((unsigned)f2bf(hn.w) << 16);
        int byte = (m * 512 + half * 256 + e4 * 8) ^ ((m & 7) << 4);
        *(uint2*)((char*)A_lds + byte) = pk;
    }
    __syncthreads();

    // ---- l=14 MFMA: 16-node tile, 2 col-groups x 5 gates ----
    f32x4 acc[2][5] = {};
    const unsigned short* Wp0 = Wb_g + (w * 16 + lr) * H2 + lc * 8;
    const unsigned short* Wp1 = Wp0 + 64 * H2;
#pragma unroll
    for (int kk = 0; kk < 8; ++kk) {
        bf16x8 a0 = *(const bf16x8*)((const char*)A_lds + swz(lr * 512 + kk * 64 + lc * 16));
#pragma unroll
        for (int g = 0; g < 5; ++g) {
            bf16x8 b0 = *(const bf16x8*)(Wp0 + g * HH * H2 + kk * 32);
            bf16x8 b1 = *(const bf16x8*)(Wp1 + g * HH * H2 + kk * 32);
            acc[0][g] = __builtin_amdgcn_mfma_f32_16x16x32_bf16(a0, b0, acc[0][g], 0, 0, 0);
            acc[1][g] = __builtin_amdgcn_mfma_f32_16x16x32_bf16(a0, b1, acc[1][g], 0, 0, 0);
        }
    }

    // ---- epilogue: per lane 4 nodes x 2 col-groups; c from LDS ----
#pragma unroll
    for (int cg = 0; cg < 2; ++cg) {
        const int ee = cg * 64 + w * 16 + lr;
        const float bi = b_iou[ee], bo = b_iou[HH + ee], bu = b_iou[2 * HH + ee];
        const float bl = b_f[ee],   br = b_f[HH + ee];
#pragma unroll
        for (int r = 0; r < 4; ++r) {
            int q    = lc * 4 + r;                    // node within tile, 0..15
            int node = node0 + q;
            int base = tree * NPT + 16383 + (node & 16383);
            int o    = base * HH + ee;
            float cl = (float)C_lds[(2 * q) * HH + ee];
            float cr = (float)C_lds[(2 * q + 1) * HH + ee];
            float hv, cv;
            GATES5(acc[cg][0][r] + bi, acc[cg][1][r] + bo, acc[cg][2][r] + bu,
                   acc[cg][3][r] + bl, acc[cg][4][r] + br, cl, cr, hv, cv);
            h_g[o]  = hv;
            c_ws[o] = (half_t)cv;
            h_bf[o] = f2bf(hv);
        }
    }
}

// ---------------- internal level (R10/R17 exact): 32-node tile ----------------
__global__ __launch_bounds__(TPB, 4) void level_k(
    int lvl,
    const float* __restrict__ b_iou, const float* __restrict__ b_f,
    float* __restrict__ h_g, half_t* __restrict__ c_ws,
    unsigned short* __restrict__ h_bf)
{
    __shared__ __align__(16) unsigned short A_lds[32 * H2];

    const int tid = threadIdx.x;
    const int w  = tid >> 6;
    const int lr = tid & 15;
    const int lc = (tid & 63) >> 4;
    const int ee = w * 16 + lr;
    const int node0 = blockIdx.x * 32;
    const int loc0  = (1 << lvl) - 1;
    const int lmask = loc0;

#pragma unroll
    for (int it = 0; it < 2; ++it) {
        int item = tid + TPB * it;
        int m = item >> 5, u = item & 31;
        int node = node0 + m;
        int tree = node >> lvl;
        int loc  = loc0 + (node & lmask);
        int coff = (tree * NPT + 2 * loc + 1 + (u >> 4)) * HH + (u & 15) * 8;
        uint4 v = *(const uint4*)(h_bf + coff);
        *(uint4*)((char*)A_lds + swz(m * 512 + u * 16)) = v;
    }
    __syncthreads();

    int   rofs[2][4];
    float clv[2][4], crv[2][4];
#pragma unroll
    for (int mt = 0; mt < 2; ++mt)
#pragma unroll
        for (int r = 0; r < 4; ++r) {
            int node = node0 + mt * 16 + lc * 4 + r;
            int tree = node >> lvl;
            int loc  = loc0 + (node & lmask);
            int base = tree * NPT + loc;
            int lrow = base + loc + 1;
            rofs[mt][r] = base * HH + ee;
            clv[mt][r] = (float)c_ws[lrow * HH + ee];
            crv[mt][r] = (float)c_ws[lrow * HH + HH + ee];
        }

    f32x4 acc[2][5] = {};
    const unsigned short* Wp = Wb_g + ee * H2 + lc * 8;
#pragma unroll
    for (int kk = 0; kk < 8; ++kk) {
        bf16x8 a0 = *(const bf16x8*)((const char*)A_lds + swz(lr * 512 + kk * 64 + lc * 16));
        bf16x8 a1 = *(const bf16x8*)((const char*)A_lds + swz((16 + lr) * 512 + kk * 64 + lc * 16));
#pragma unroll
        for (int g = 0; g < 5; ++g) {
            bf16x8 b = *(const bf16x8*)(Wp + g * HH * H2 + kk * 32);
            acc[0][g] = __builtin_amdgcn_mfma_f32_16x16x32_bf16(a0, b, acc[0][g], 0, 0, 0);
            acc[1][g] = __builtin_amdgcn_mfma_f32_16x16x32_bf16(a1, b, acc[1][g], 0, 0, 0);
        }
    }

    const float bi = b_iou[ee], bo = b_iou[HH + ee], bu = b_iou[2 * HH + ee];
    const float bl = b_f[ee],   br = b_f[HH + ee];
#pragma unroll
    for (int mt = 0; mt < 2; ++mt)
#pragma unroll
        for (int r = 0; r < 4; ++r) {
            float hv, cv;
            GATES5(acc[mt][0][r] + bi, acc[mt][1][r] + bo, acc[mt][2][r] + bu,
                   acc[mt][3][r] + bl, acc[mt][4][r] + br, clv[mt][r], crv[mt][r], hv, cv);
            int o = rofs[mt][r];
            h_g[o]  = hv;
            c_ws[o] = (half_t)cv;
            h_bf[o] = f2bf(hv);
        }
}

// ---------------- solo tail l=5..0: one block per tree, weights in registers ----------------
__global__ __launch_bounds__(TPB, 2) void solo_k(
    const float* __restrict__ b_iou, const float* __restrict__ b_f,
    float* __restrict__ h_g, half_t* __restrict__ c_ws,
    const unsigned short* __restrict__ h_bf)
{
    __shared__ __align__(16) unsigned char hb[32768];

    const int tid = threadIdx.x;
    const int w = tid >> 6, lr = tid & 15, lc = (tid & 63) >> 4;
    const int ee = w * 16 + lr;
    const int tb = blockIdx.x * NPT;
    const float bi = b_iou[ee], bo = b_iou[HH + ee], bu = b_iou[2 * HH + ee];
    const float bl = b_f[ee],   br = b_f[HH + ee];

    bf16x8 Bf[5][8];
    const unsigned short* Wp = Wb_g + ee * H2 + lc * 8;
#pragma unroll
    for (int g = 0; g < 5; ++g)
#pragma unroll
        for (int kk = 0; kk < 8; ++kk)
            Bf[g][kk] = *(const bf16x8*)(Wp + g * HH * H2 + kk * 32);

#pragma unroll
    for (int it = 0; it < 2; ++it) {
        int p = tid + TPB * it;
        int cc = p >> 4, q = p & 15;
        uint4 v = *(const uint4*)(h_bf + (tb + 63 + cc) * HH + q * 8);
        *(uint4*)(hb + swz(p * 16)) = v;
    }

#pragma unroll 1
    for (int l = 5; l >= 0; --l) {
        const int nl     = 1 << l;
        const int loc0   = nl - 1;
        const int cloc0  = 2 * nl - 1;
        const int cbase  = (l & 1) ? 0 : 16384;
        const int obase  = cbase ^ 16384;
        const bool mt1   = (nl > 16);

        __syncthreads();

        f32x4 acc[2][5] = {};
#pragma unroll
        for (int kk = 0; kk < 8; ++kk) {
            bf16x8 a0 = *(const bf16x8*)(hb + cbase + swz(lr * 512 + kk * 64 + lc * 16));
#pragma unroll
            for (int g = 0; g < 5; ++g)
                acc[0][g] = __builtin_amdgcn_mfma_f32_16x16x32_bf16(a0, Bf[g][kk], acc[0][g], 0, 0, 0);
            if (mt1) {
                bf16x8 a1 = *(const bf16x8*)(hb + cbase + swz((16 + lr) * 512 + kk * 64 + lc * 16));
#pragma unroll
                for (int g = 0; g < 5; ++g)
                    acc[1][g] = __builtin_amdgcn_mfma_f32_16x16x32_bf16(a1, Bf[g][kk], acc[1][g], 0, 0, 0);
            }
        }
        __syncthreads();

#pragma unroll
        for (int mt = 0; mt < 2; ++mt)
#pragma unroll
            for (int r = 0; r < 4; ++r) {
                int j = mt * 16 + lc * 4 + r;
                if (j >= nl) continue;
                int row  = tb + loc0 + j;
                int lrow = tb + cloc0 + 2 * j;
                float cl = (float)c_ws[lrow * HH + ee];
                float cr = (float)c_ws[lrow * HH + HH + ee];
                float hv, cv;
                GATES5(acc[mt][0][r] + bi, acc[mt][1][r] + bo, acc[mt][2][r] + bu,
                       acc[mt][3][r] + bl, acc[mt][4][r] + br, cl, cr, hv, cv);
                h_g[row * HH + ee]  = hv;
                c_ws[row * HH + ee] = (half_t)cv;
                *(unsigned short*)(hb + obase + swz(j * 256 + ee * 2)) = f2bf(hv);
            }
    }
}

extern "C" void kernel_launch(void* const* d_in, const int* in_sizes, int n_in,
                              void* d_out, int out_size, void* d_ws, size_t ws_size,
                              hipStream_t stream)
{
    const float* iou   = (const float*)d_in[0];
    const float* c_in  = (const float*)d_in[2];
    const float* W_iou = (const float*)d_in[3];
    const float* b_iou = (const float*)d_in[4];
    const float* W_f   = (const float*)d_in[5];
    const float* b_f   = (const float*)d_in[6];
    float* h_out = (float*)d_out;
    half_t* c_ws = (half_t*)d_ws;                                                       // 67 MiB f16 c
    unsigned short* h_bf = (unsigned short*)((char*)d_ws + (size_t)72 * 1024 * 1024);   // 67 MiB bf16 h

    conv_k<<<160, 256, 0, stream>>>(W_iou, W_f);
    leaf14_k<<<4096, 256, 0, stream>>>(iou, c_in, b_iou, b_f, h_out, c_ws, h_bf);   // leaves + l=14
    for (int l = 13; l >= 6; --l) {
        int blocks = (4 << l) / 32;
        level_k<<<blocks, TPB, 0, stream>>>(l, b_iou, b_f, h_out, c_ws, h_bf);
    }
    solo_k<<<4, TPB, 0, stream>>>(b_iou, b_f, h_out, c_ws, h_bf);
}

// Round 20
// 341.569 us; speedup vs baseline: 1.1491x; 1.1491x over previous
//
#include <hip/hip_runtime.h>

#define HH   128
#define H2   256
#define H3   384
#define NPT  65535      // nodes per tree (2^16 - 1)
#define TPB  512

typedef __bf16    bf16x8 __attribute__((ext_vector_type(8)));
typedef float     f32x4  __attribute__((ext_vector_type(4)));
typedef _Float16  f16x4  __attribute__((ext_vector_type(4)));
typedef _Float16  half_t;

__device__ unsigned short Wb_g[640 * 256];   // bf16 [row=output col j][k]; j<384: W_iou, else W_f

__device__ __forceinline__ float fsig(float x)  { return 1.0f / (1.0f + __expf(-x)); }
__device__ __forceinline__ float ftanh(float x) { return 1.0f - 2.0f / (__expf(2.0f * x) + 1.0f); }
__device__ __forceinline__ unsigned short f2bf(float f) {   // RNE fp32->bf16
    unsigned u = __float_as_uint(f);
    u += 0x7fffu + ((u >> 16) & 1u);
    return (unsigned short)(u >> 16);
}
__device__ __forceinline__ int swz(int off) { return off ^ (((off >> 9) & 7) << 4); }

// ---------------- weight convert ----------------
__global__ __launch_bounds__(256) void conv_k(const float* __restrict__ W_iou,
                                              const float* __restrict__ W_f)
{
    int t    = blockIdx.x * 256 + threadIdx.x;
    int base = t * 4;
    int j = base >> 8, k = base & 255;
    const float* src = (j < H3) ? (W_iou + j * H2 + k)
                                : (W_f + (j - H3) * H2 + k);
    float4 v = *(const float4*)src;
    ushort4 p;
    p.x = f2bf(v.x); p.y = f2bf(v.y); p.z = f2bf(v.z); p.w = f2bf(v.w);
    *(ushort4*)(Wb_g + base) = p;
}

#define GATES5(PI, PO, PU, PL, PR, CL, CR, HV, CV) \
    { CV = fsig(PI) * ftanh(PU) + fsig(PL) * (CL) + fsig(PR) * (CR); \
      HV = fsig(PO) * ftanh(CV); }

// ---------------- fused leaf + l=14 (R17 structure + XCD swizzle + NT hints) ----------------
// Block bs owns l=14 nodes [32bs, 32bs+32) and their 64 leaf children. Leaf phase
// computes gates elementwise: h -> h_g (NT store) + swizzled LDS A-tile, c -> LDS.
// l=14 phase = MFMA + epilogue with child-c from LDS. iou/c_in are read-once ->
// NT loads; h_g is write-only -> NT stores; h_bf/c_ws stay cached (reused next level).
__global__ __launch_bounds__(TPB, 4) void leaf14_k(
    const float* __restrict__ iou, const float* __restrict__ c_in,
    const float* __restrict__ b_iou, const float* __restrict__ b_f,
    float* __restrict__ h_g, half_t* __restrict__ c_ws,
    unsigned short* __restrict__ h_bf)
{
    __shared__ __align__(16) unsigned short A_lds[32 * H2];   // 16 KB: h of 64 leaves, A-layout
    __shared__ __align__(16) half_t         C_lds[64 * HH];   // 16 KB: c of 64 leaves

    const int tid = threadIdx.x;
    const int w  = tid >> 6;
    const int lr = tid & 15;
    const int lc = (tid & 63) >> 4;
    const int ee = w * 16 + lr;
    const int nb = gridDim.x;
    const int bs = (blockIdx.x & 7) * (nb >> 3) + (blockIdx.x >> 3);   // XCD-chunked
    const int node0 = bs * 32;
    const int tree  = node0 >> 14;
    const int lbase = tree * NPT + 32767 + 2 * (node0 & 16383);   // first leaf row

    // ---- leaf phase: 2048 float4-items over [64 rows][32 float4] ----
#pragma unroll
    for (int it = 0; it < 4; ++it) {
        int p   = tid + TPB * it;
        int row = p >> 5;            // 0..63
        int e4  = p & 31;
        int grow = lbase + row;
        const float* ip = iou + (size_t)grow * H3 + e4 * 4;
        f32x4 vi = __builtin_nontemporal_load((const f32x4*)(ip));
        f32x4 vo = __builtin_nontemporal_load((const f32x4*)(ip + HH));
        f32x4 vu = __builtin_nontemporal_load((const f32x4*)(ip + 2 * HH));
        f32x4 vc = __builtin_nontemporal_load((const f32x4*)(c_in + (size_t)grow * HH + e4 * 4));
        float4 bi4 = *(const float4*)(b_iou + e4 * 4);
        float4 bo4 = *(const float4*)(b_iou + HH + e4 * 4);
        float4 bu4 = *(const float4*)(b_iou + 2 * HH + e4 * 4);

        f32x4 hn, cn;
#define DOL(X) { float iv = fsig(vi.X + bi4.X); float ov = fsig(vo.X + bo4.X); \
                 float uv = ftanh(vu.X + bu4.X); float cv = iv * uv + vc.X;    \
                 cn.X = cv; hn.X = ov * ftanh(cv); }
        DOL(x) DOL(y) DOL(z) DOL(w)
#undef DOL
        __builtin_nontemporal_store(hn, (f32x4*)(h_g + (size_t)grow * HH + e4 * 4));
        f16x4 cf; cf.x = (half_t)cn.x; cf.y = (half_t)cn.y;
        cf.z = (half_t)cn.z; cf.w = (half_t)cn.w;
        *(f16x4*)(C_lds + row * HH + e4 * 4) = cf;                   // c -> LDS only
        int m = row >> 1, half = row & 1;                            // A[m][half*128 + e]
        uint2 pk;
        pk.x = (unsigned)f2bf(hn.x) | ((unsigned)f2bf(hn.y) << 16);
        pk.y = (unsigned)f2bf(hn.z) | ((unsigned)f2bf(hn.w) << 16);
        int byte = (m * 512 + half * 256 + e4 * 8) ^ ((m & 7) << 4); // swizzled (8B-safe)
        *(uint2*)((char*)A_lds + byte) = pk;
    }
    __syncthreads();

    // ---- l=14 phase: MFMA from LDS, c from LDS ----
    f32x4 acc[2][5] = {};
    const unsigned short* Wp = Wb_g + ee * H2 + lc * 8;
#pragma unroll
    for (int kk = 0; kk < 8; ++kk) {
        bf16x8 a0 = *(const bf16x8*)((const char*)A_lds + swz(lr * 512 + kk * 64 + lc * 16));
        bf16x8 a1 = *(const bf16x8*)((const char*)A_lds + swz((16 + lr) * 512 + kk * 64 + lc * 16));
#pragma unroll
        for (int g = 0; g < 5; ++g) {
            bf16x8 b = *(const bf16x8*)(Wp + g * HH * H2 + kk * 32);
            acc[0][g] = __builtin_amdgcn_mfma_f32_16x16x32_bf16(a0, b, acc[0][g], 0, 0, 0);
            acc[1][g] = __builtin_amdgcn_mfma_f32_16x16x32_bf16(a1, b, acc[1][g], 0, 0, 0);
        }
    }

    const float bi = b_iou[ee], bo = b_iou[HH + ee], bu = b_iou[2 * HH + ee];
    const float bl = b_f[ee],   br = b_f[HH + ee];
#pragma unroll
    for (int mt = 0; mt < 2; ++mt)
#pragma unroll
        for (int r = 0; r < 4; ++r) {
            int q    = mt * 16 + lc * 4 + r;           // node within tile
            int node = node0 + q;
            int base = tree * NPT + 16383 + (node & 16383);
            int o    = base * HH + ee;
            float cl = (float)C_lds[(2 * q) * HH + ee];
            float cr = (float)C_lds[(2 * q + 1) * HH + ee];
            float hv, cv;
            GATES5(acc[mt][0][r] + bi, acc[mt][1][r] + bo, acc[mt][2][r] + bu,
                   acc[mt][3][r] + bl, acc[mt][4][r] + br, cl, cr, hv, cv);
            __builtin_nontemporal_store(hv, h_g + o);
            c_ws[o] = (half_t)cv;
            h_bf[o] = f2bf(hv);
        }
}

// ---------------- internal level (R17 structure + XCD swizzle + NT h_g store) ----------------
__global__ __launch_bounds__(TPB, 4) void level_k(
    int lvl,
    const float* __restrict__ b_iou, const float* __restrict__ b_f,
    float* __restrict__ h_g, half_t* __restrict__ c_ws,
    unsigned short* __restrict__ h_bf)
{
    __shared__ __align__(16) unsigned short A_lds[32 * H2];

    const int tid = threadIdx.x;
    const int w  = tid >> 6;
    const int lr = tid & 15;
    const int lc = (tid & 63) >> 4;
    const int ee = w * 16 + lr;
    const int nb = gridDim.x;
    const int bs = (nb >= 8) ? ((blockIdx.x & 7) * (nb >> 3) + (blockIdx.x >> 3))
                             : blockIdx.x;
    const int node0 = bs * 32;
    const int loc0  = (1 << lvl) - 1;
    const int lmask = loc0;

#pragma unroll
    for (int it = 0; it < 2; ++it) {
        int item = tid + TPB * it;
        int m = item >> 5, u = item & 31;
        int node = node0 + m;
        int tree = node >> lvl;
        int loc  = loc0 + (node & lmask);
        int coff = (tree * NPT + 2 * loc + 1 + (u >> 4)) * HH + (u & 15) * 8;
        uint4 v = *(const uint4*)(h_bf + coff);
        *(uint4*)((char*)A_lds + swz(m * 512 + u * 16)) = v;
    }
    __syncthreads();

    int   rofs[2][4];
    float clv[2][4], crv[2][4];
#pragma unroll
    for (int mt = 0; mt < 2; ++mt)
#pragma unroll
        for (int r = 0; r < 4; ++r) {
            int node = node0 + mt * 16 + lc * 4 + r;
            int tree = node >> lvl;
            int loc  = loc0 + (node & lmask);
            int base = tree * NPT + loc;
            int lrow = base + loc + 1;
            rofs[mt][r] = base * HH + ee;
            clv[mt][r] = (float)c_ws[lrow * HH + ee];
            crv[mt][r] = (float)c_ws[lrow * HH + HH + ee];
        }

    f32x4 acc[2][5] = {};
    const unsigned short* Wp = Wb_g + ee * H2 + lc * 8;
#pragma unroll
    for (int kk = 0; kk < 8; ++kk) {
        bf16x8 a0 = *(const bf16x8*)((const char*)A_lds + swz(lr * 512 + kk * 64 + lc * 16));
        bf16x8 a1 = *(const bf16x8*)((const char*)A_lds + swz((16 + lr) * 512 + kk * 64 + lc * 16));
#pragma unroll
        for (int g = 0; g < 5; ++g) {
            bf16x8 b = *(const bf16x8*)(Wp + g * HH * H2 + kk * 32);
            acc[0][g] = __builtin_amdgcn_mfma_f32_16x16x32_bf16(a0, b, acc[0][g], 0, 0, 0);
            acc[1][g] = __builtin_amdgcn_mfma_f32_16x16x32_bf16(a1, b, acc[1][g], 0, 0, 0);
        }
    }

    const float bi = b_iou[ee], bo = b_iou[HH + ee], bu = b_iou[2 * HH + ee];
    const float bl = b_f[ee],   br = b_f[HH + ee];
#pragma unroll
    for (int mt = 0; mt < 2; ++mt)
#pragma unroll
        for (int r = 0; r < 4; ++r) {
            float hv, cv;
            GATES5(acc[mt][0][r] + bi, acc[mt][1][r] + bo, acc[mt][2][r] + bu,
                   acc[mt][3][r] + bl, acc[mt][4][r] + br, clv[mt][r], crv[mt][r], hv, cv);
            int o = rofs[mt][r];
            __builtin_nontemporal_store(hv, h_g + o);
            c_ws[o] = (half_t)cv;
            h_bf[o] = f2bf(hv);
        }
}

// ---------------- solo tail l=5..0: one block per tree, weights in registers ----------------
__global__ __launch_bounds__(TPB, 2) void solo_k(
    const float* __restrict__ b_iou, const float* __restrict__ b_f,
    float* __restrict__ h_g, half_t* __restrict__ c_ws,
    const unsigned short* __restrict__ h_bf)
{
    __shared__ __align__(16) unsigned char hb[32768];

    const int tid = threadIdx.x;
    const int w = tid >> 6, lr = tid & 15, lc = (tid & 63) >> 4;
    const int ee = w * 16 + lr;
    const int tb = blockIdx.x * NPT;
    const float bi = b_iou[ee], bo = b_iou[HH + ee], bu = b_iou[2 * HH + ee];
    const float bl = b_f[ee],   br = b_f[HH + ee];

    bf16x8 Bf[5][8];
    const unsigned short* Wp = Wb_g + ee * H2 + lc * 8;
#pragma unroll
    for (int g = 0; g < 5; ++g)
#pragma unroll
        for (int kk = 0; kk < 8; ++kk)
            Bf[g][kk] = *(const bf16x8*)(Wp + g * HH * H2 + kk * 32);

#pragma unroll
    for (int it = 0; it < 2; ++it) {
        int p = tid + TPB * it;
        int cc = p >> 4, q = p & 15;
        uint4 v = *(const uint4*)(h_bf + (tb + 63 + cc) * HH + q * 8);
        *(uint4*)(hb + swz(p * 16)) = v;
    }

#pragma unroll 1
    for (int l = 5; l >= 0; --l) {
        const int nl     = 1 << l;
        const int loc0   = nl - 1;
        const int cloc0  = 2 * nl - 1;
        const int cbase  = (l & 1) ? 0 : 16384;
        const int obase  = cbase ^ 16384;
        const bool mt1   = (nl > 16);

        __syncthreads();

        f32x4 acc[2][5] = {};
#pragma unroll
        for (int kk = 0; kk < 8; ++kk) {
            bf16x8 a0 = *(const bf16x8*)(hb + cbase + swz(lr * 512 + kk * 64 + lc * 16));
#pragma unroll
            for (int g = 0; g < 5; ++g)
                acc[0][g] = __builtin_amdgcn_mfma_f32_16x16x32_bf16(a0, Bf[g][kk], acc[0][g], 0, 0, 0);
            if (mt1) {
                bf16x8 a1 = *(const bf16x8*)(hb + cbase + swz((16 + lr) * 512 + kk * 64 + lc * 16));
#pragma unroll
                for (int g = 0; g < 5; ++g)
                    acc[1][g] = __builtin_amdgcn_mfma_f32_16x16x32_bf16(a1, Bf[g][kk], acc[1][g], 0, 0, 0);
            }
        }
        __syncthreads();

#pragma unroll
        for (int mt = 0; mt < 2; ++mt)
#pragma unroll
            for (int r = 0; r < 4; ++r) {
                int j = mt * 16 + lc * 4 + r;
                if (j >= nl) continue;
                int row  = tb + loc0 + j;
                int lrow = tb + cloc0 + 2 * j;
                float cl = (float)c_ws[lrow * HH + ee];
                float cr = (float)c_ws[lrow * HH + HH + ee];
                float hv, cv;
                GATES5(acc[mt][0][r] + bi, acc[mt][1][r] + bo, acc[mt][2][r] + bu,
                       acc[mt][3][r] + bl, acc[mt][4][r] + br, cl, cr, hv, cv);
                h_g[row * HH + ee]  = hv;
                c_ws[row * HH + ee] = (half_t)cv;
                *(unsigned short*)(hb + obase + swz(j * 256 + ee * 2)) = f2bf(hv);
            }
    }
}

extern "C" void kernel_launch(void* const* d_in, const int* in_sizes, int n_in,
                              void* d_out, int out_size, void* d_ws, size_t ws_size,
                              hipStream_t stream)
{
    const float* iou   = (const float*)d_in[0];
    const float* c_in  = (const float*)d_in[2];
    const float* W_iou = (const float*)d_in[3];
    const float* b_iou = (const float*)d_in[4];
    const float* W_f   = (const float*)d_in[5];
    const float* b_f   = (const float*)d_in[6];
    float* h_out = (float*)d_out;
    half_t* c_ws = (half_t*)d_ws;                                                       // 67 MiB f16 c
    unsigned short* h_bf = (unsigned short*)((char*)d_ws + (size_t)72 * 1024 * 1024);   // 67 MiB bf16 h

    conv_k<<<160, 256, 0, stream>>>(W_iou, W_f);
    leaf14_k<<<2048, TPB, 0, stream>>>(iou, c_in, b_iou, b_f, h_out, c_ws, h_bf);   // leaves + l=14
    for (int l = 13; l >= 6; --l) {
        int blocks = (4 << l) / 32;
        level_k<<<blocks, TPB, 0, stream>>>(l, b_iou, b_f, h_out, c_ws, h_bf);
    }
    solo_k<<<4, TPB, 0, stream>>>(b_iou, b_f, h_out, c_ws, h_bf);
}

// Round 22
// 338.314 us; speedup vs baseline: 1.1601x; 1.0096x over previous
//
#include <hip/hip_runtime.h>

#define HH   128
#define H2   256
#define H3   384
#define NPT  65535      // nodes per tree (2^16 - 1)
#define TPB  512

typedef __bf16    bf16x8 __attribute__((ext_vector_type(8)));
typedef float     f32x4  __attribute__((ext_vector_type(4)));
typedef _Float16  f16x4  __attribute__((ext_vector_type(4)));
typedef _Float16  half_t;

__device__ unsigned short Wb_g[640 * 256];   // bf16 [row=output col j][k]; j<384: W_iou, else W_f

__device__ __forceinline__ float fsig(float x)  { return 1.0f / (1.0f + __expf(-x)); }
__device__ __forceinline__ float ftanh(float x) { return 1.0f - 2.0f / (__expf(2.0f * x) + 1.0f); }
__device__ __forceinline__ unsigned short f2bf(float f) {   // RNE fp32->bf16
    unsigned u = __float_as_uint(f);
    u += 0x7fffu + ((u >> 16) & 1u);
    return (unsigned short)(u >> 16);
}
__device__ __forceinline__ int swz(int off) { return off ^ (((off >> 9) & 7) << 4); }

// ---------------- weight convert ----------------
__global__ __launch_bounds__(256) void conv_k(const float* __restrict__ W_iou,
                                              const float* __restrict__ W_f)
{
    int t    = blockIdx.x * 256 + threadIdx.x;
    int base = t * 4;
    int j = base >> 8, k = base & 255;
    const float* src = (j < H3) ? (W_iou + j * H2 + k)
                                : (W_f + (j - H3) * H2 + k);
    float4 v = *(const float4*)src;
    ushort4 p;
    p.x = f2bf(v.x); p.y = f2bf(v.y); p.z = f2bf(v.z); p.w = f2bf(v.w);
    *(ushort4*)(Wb_g + base) = p;
}

#define GATES5(PI, PO, PU, PL, PR, CL, CR, HV, CV) \
    { CV = fsig(PI) * ftanh(PU) + fsig(PL) * (CL) + fsig(PR) * (CR); \
      HV = fsig(PO) * ftanh(CV); }

// ---------------- fused leaf + l=14 (R20 exact) ----------------
__global__ __launch_bounds__(TPB, 4) void leaf14_k(
    const float* __restrict__ iou, const float* __restrict__ c_in,
    const float* __restrict__ b_iou, const float* __restrict__ b_f,
    float* __restrict__ h_g, half_t* __restrict__ c_ws,
    unsigned short* __restrict__ h_bf)
{
    __shared__ __align__(16) unsigned short A_lds[32 * H2];   // 16 KB: h of 64 leaves, A-layout
    __shared__ __align__(16) half_t         C_lds[64 * HH];   // 16 KB: c of 64 leaves

    const int tid = threadIdx.x;
    const int w  = tid >> 6;
    const int lr = tid & 15;
    const int lc = (tid & 63) >> 4;
    const int ee = w * 16 + lr;
    const int nb = gridDim.x;
    const int bs = (blockIdx.x & 7) * (nb >> 3) + (blockIdx.x >> 3);   // XCD-chunked
    const int node0 = bs * 32;
    const int tree  = node0 >> 14;
    const int lbase = tree * NPT + 32767 + 2 * (node0 & 16383);   // first leaf row

#pragma unroll
    for (int it = 0; it < 4; ++it) {
        int p   = tid + TPB * it;
        int row = p >> 5;            // 0..63
        int e4  = p & 31;
        int grow = lbase + row;
        const float* ip = iou + (size_t)grow * H3 + e4 * 4;
        f32x4 vi = __builtin_nontemporal_load((const f32x4*)(ip));
        f32x4 vo = __builtin_nontemporal_load((const f32x4*)(ip + HH));
        f32x4 vu = __builtin_nontemporal_load((const f32x4*)(ip + 2 * HH));
        f32x4 vc = __builtin_nontemporal_load((const f32x4*)(c_in + (size_t)grow * HH + e4 * 4));
        float4 bi4 = *(const float4*)(b_iou + e4 * 4);
        float4 bo4 = *(const float4*)(b_iou + HH + e4 * 4);
        float4 bu4 = *(const float4*)(b_iou + 2 * HH + e4 * 4);

        f32x4 hn, cn;
#define DOL(X) { float iv = fsig(vi.X + bi4.X); float ov = fsig(vo.X + bo4.X); \
                 float uv = ftanh(vu.X + bu4.X); float cv = iv * uv + vc.X;    \
                 cn.X = cv; hn.X = ov * ftanh(cv); }
        DOL(x) DOL(y) DOL(z) DOL(w)
#undef DOL
        __builtin_nontemporal_store(hn, (f32x4*)(h_g + (size_t)grow * HH + e4 * 4));
        f16x4 cf; cf.x = (half_t)cn.x; cf.y = (half_t)cn.y;
        cf.z = (half_t)cn.z; cf.w = (half_t)cn.w;
        *(f16x4*)(C_lds + row * HH + e4 * 4) = cf;
        int m = row >> 1, half = row & 1;
        uint2 pk;
        pk.x = (unsigned)f2bf(hn.x) | ((unsigned)f2bf(hn.y) << 16);
        pk.y = (unsigned)f2bf(hn.z) | ((unsigned)f2bf(hn.w) << 16);
        int byte = (m * 512 + half * 256 + e4 * 8) ^ ((m & 7) << 4);
        *(uint2*)((char*)A_lds + byte) = pk;
    }
    __syncthreads();

    f32x4 acc[2][5] = {};
    const unsigned short* Wp = Wb_g + ee * H2 + lc * 8;
#pragma unroll
    for (int kk = 0; kk < 8; ++kk) {
        bf16x8 a0 = *(const bf16x8*)((const char*)A_lds + swz(lr * 512 + kk * 64 + lc * 16));
        bf16x8 a1 = *(const bf16x8*)((const char*)A_lds + swz((16 + lr) * 512 + kk * 64 + lc * 16));
#pragma unroll
        for (int g = 0; g < 5; ++g) {
            bf16x8 b = *(const bf16x8*)(Wp + g * HH * H2 + kk * 32);
            acc[0][g] = __builtin_amdgcn_mfma_f32_16x16x32_bf16(a0, b, acc[0][g], 0, 0, 0);
            acc[1][g] = __builtin_amdgcn_mfma_f32_16x16x32_bf16(a1, b, acc[1][g], 0, 0, 0);
        }
    }

    const float bi = b_iou[ee], bo = b_iou[HH + ee], bu = b_iou[2 * HH + ee];
    const float bl = b_f[ee],   br = b_f[HH + ee];
#pragma unroll
    for (int mt = 0; mt < 2; ++mt)
#pragma unroll
        for (int r = 0; r < 4; ++r) {
            int q    = mt * 16 + lc * 4 + r;
            int node = node0 + q;
            int base = tree * NPT + 16383 + (node & 16383);
            int o    = base * HH + ee;
            float cl = (float)C_lds[(2 * q) * HH + ee];
            float cr = (float)C_lds[(2 * q + 1) * HH + ee];
            float hv, cv;
            GATES5(acc[mt][0][r] + bi, acc[mt][1][r] + bo, acc[mt][2][r] + bu,
                   acc[mt][3][r] + bl, acc[mt][4][r] + br, cl, cr, hv, cv);
            __builtin_nontemporal_store(hv, h_g + o);
            c_ws[o] = (half_t)cv;
            h_bf[o] = f2bf(hv);
        }
}

// ---------------- internal level (R20 exact): 32-node tile, l = 13..7 ----------------
__global__ __launch_bounds__(TPB, 4) void level_k(
    int lvl,
    const float* __restrict__ b_iou, const float* __restrict__ b_f,
    float* __restrict__ h_g, half_t* __restrict__ c_ws,
    unsigned short* __restrict__ h_bf)
{
    __shared__ __align__(16) unsigned short A_lds[32 * H2];

    const int tid = threadIdx.x;
    const int w  = tid >> 6;
    const int lr = tid & 15;
    const int lc = (tid & 63) >> 4;
    const int ee = w * 16 + lr;
    const int nb = gridDim.x;
    const int bs = (nb >= 8) ? ((blockIdx.x & 7) * (nb >> 3) + (blockIdx.x >> 3))
                             : blockIdx.x;
    const int node0 = bs * 32;
    const int loc0  = (1 << lvl) - 1;
    const int lmask = loc0;

#pragma unroll
    for (int it = 0; it < 2; ++it) {
        int item = tid + TPB * it;
        int m = item >> 5, u = item & 31;
        int node = node0 + m;
        int tree = node >> lvl;
        int loc  = loc0 + (node & lmask);
        int coff = (tree * NPT + 2 * loc + 1 + (u >> 4)) * HH + (u & 15) * 8;
        uint4 v = *(const uint4*)(h_bf + coff);
        *(uint4*)((char*)A_lds + swz(m * 512 + u * 16)) = v;
    }
    __syncthreads();

    int   rofs[2][4];
    float clv[2][4], crv[2][4];
#pragma unroll
    for (int mt = 0; mt < 2; ++mt)
#pragma unroll
        for (int r = 0; r < 4; ++r) {
            int node = node0 + mt * 16 + lc * 4 + r;
            int tree = node >> lvl;
            int loc  = loc0 + (node & lmask);
            int base = tree * NPT + loc;
            int lrow = base + loc + 1;
            rofs[mt][r] = base * HH + ee;
            clv[mt][r] = (float)c_ws[lrow * HH + ee];
            crv[mt][r] = (float)c_ws[lrow * HH + HH + ee];
        }

    f32x4 acc[2][5] = {};
    const unsigned short* Wp = Wb_g + ee * H2 + lc * 8;
#pragma unroll
    for (int kk = 0; kk < 8; ++kk) {
        bf16x8 a0 = *(const bf16x8*)((const char*)A_lds + swz(lr * 512 + kk * 64 + lc * 16));
        bf16x8 a1 = *(const bf16x8*)((const char*)A_lds + swz((16 + lr) * 512 + kk * 64 + lc * 16));
#pragma unroll
        for (int g = 0; g < 5; ++g) {
            bf16x8 b = *(const bf16x8*)(Wp + g * HH * H2 + kk * 32);
            acc[0][g] = __builtin_amdgcn_mfma_f32_16x16x32_bf16(a0, b, acc[0][g], 0, 0, 0);
            acc[1][g] = __builtin_amdgcn_mfma_f32_16x16x32_bf16(a1, b, acc[1][g], 0, 0, 0);
        }
    }

    const float bi = b_iou[ee], bo = b_iou[HH + ee], bu = b_iou[2 * HH + ee];
    const float bl = b_f[ee],   br = b_f[HH + ee];
#pragma unroll
    for (int mt = 0; mt < 2; ++mt)
#pragma unroll
        for (int r = 0; r < 4; ++r) {
            float hv, cv;
            GATES5(acc[mt][0][r] + bi, acc[mt][1][r] + bo, acc[mt][2][r] + bu,
                   acc[mt][3][r] + bl, acc[mt][4][r] + br, clv[mt][r], crv[mt][r], hv, cv);
            int o = rofs[mt][r];
            __builtin_nontemporal_store(hv, h_g + o);
            c_ws[o] = (half_t)cv;
            h_bf[o] = f2bf(hv);
        }
}

// ---------------- solo tail l=6..0: one block per tree, weights in registers ----------------
// LDS: [0,32K) = l=7 h (A-layout for l=6's two 32-node tiles); [32K,48K) = l=6 h out.
// Then l=5..0 ping-pong: l=5 reads 32K, writes 0; l=4 reads 0 writes 16K; etc.
__global__ __launch_bounds__(TPB, 2) void solo_k(
    const float* __restrict__ b_iou, const float* __restrict__ b_f,
    float* __restrict__ h_g, half_t* __restrict__ c_ws,
    const unsigned short* __restrict__ h_bf)
{
    __shared__ __align__(16) unsigned char hb[49152];

    const int tid = threadIdx.x;
    const int w = tid >> 6, lr = tid & 15, lc = (tid & 63) >> 4;
    const int ee = w * 16 + lr;
    const int tb = blockIdx.x * NPT;
    const float bi = b_iou[ee], bo = b_iou[HH + ee], bu = b_iou[2 * HH + ee];
    const float bl = b_f[ee],   br = b_f[HH + ee];

    bf16x8 Bf[5][8];
    const unsigned short* Wp = Wb_g + ee * H2 + lc * 8;
#pragma unroll
    for (int g = 0; g < 5; ++g)
#pragma unroll
        for (int kk = 0; kk < 8; ++kk)
            Bf[g][kk] = *(const bf16x8*)(Wp + g * HH * H2 + kk * 32);

    // ---- stage l=7 h: 128 rows x 256B = 32 KB (rows tb+127 .. tb+254) ----
#pragma unroll
    for (int it = 0; it < 4; ++it) {
        int p = tid + TPB * it;            // 2048 chunks of 16B
        int cc = p >> 4, q = p & 15;
        uint4 v = *(const uint4*)(h_bf + (tb + 127 + cc) * HH + q * 8);
        *(uint4*)(hb + swz(p * 16)) = v;
    }
    __syncthreads();

    // ---- l=6: 64 nodes = two 32-node tiles; children h from LDS, c from global ----
#pragma unroll 1
    for (int tt = 0; tt < 2; ++tt) {
        f32x4 acc[2][5] = {};
#pragma unroll
        for (int kk = 0; kk < 8; ++kk) {
            bf16x8 a0 = *(const bf16x8*)(hb + swz(tt * 16384 + lr * 512 + kk * 64 + lc * 16));
            bf16x8 a1 = *(const bf16x8*)(hb + swz(tt * 16384 + (16 + lr) * 512 + kk * 64 + lc * 16));
#pragma unroll
            for (int g = 0; g < 5; ++g) {
                acc[0][g] = __builtin_amdgcn_mfma_f32_16x16x32_bf16(a0, Bf[g][kk], acc[0][g], 0, 0, 0);
                acc[1][g] = __builtin_amdgcn_mfma_f32_16x16x32_bf16(a1, Bf[g][kk], acc[1][g], 0, 0, 0);
            }
        }
#pragma unroll
        for (int mt = 0; mt < 2; ++mt)
#pragma unroll
            for (int r = 0; r < 4; ++r) {
                int j    = tt * 32 + mt * 16 + lc * 4 + r;   // l=6 node 0..63
                int row  = tb + 63 + j;
                int lrow = tb + 127 + 2 * j;
                float cl = (float)c_ws[lrow * HH + ee];
                float cr = (float)c_ws[lrow * HH + HH + ee];
                float hv, cv;
                GATES5(acc[mt][0][r] + bi, acc[mt][1][r] + bo, acc[mt][2][r] + bu,
                       acc[mt][3][r] + bl, acc[mt][4][r] + br, cl, cr, hv, cv);
                h_g[row * HH + ee]  = hv;
                c_ws[row * HH + ee] = (half_t)cv;
                *(unsigned short*)(hb + 32768 + swz(j * 256 + ee * 2)) = f2bf(hv);
            }
    }

    // ---- l=5..0: ping-pong (l=5 reads the 32K l=6-out region) ----
#pragma unroll 1
    for (int l = 5; l >= 0; --l) {
        const int nl     = 1 << l;
        const int loc0   = nl - 1;
        const int cloc0  = 2 * nl - 1;
        const int cbase  = (l == 5) ? 32768 : ((l & 1) ? 16384 : 0);
        const int obase  = (l == 5) ? 0 : (((l & 1) ? 16384 : 0) ^ 16384);
        const bool mt1   = (nl > 16);

        __syncthreads();

        f32x4 acc[2][5] = {};
#pragma unroll
        for (int kk = 0; kk < 8; ++kk) {
            bf16x8 a0 = *(const bf16x8*)(hb + cbase + swz(lr * 512 + kk * 64 + lc * 16));
#pragma unroll
            for (int g = 0; g < 5; ++g)
                acc[0][g] = __builtin_amdgcn_mfma_f32_16x16x32_bf16(a0, Bf[g][kk], acc[0][g], 0, 0, 0);
            if (mt1) {
                bf16x8 a1 = *(const bf16x8*)(hb + cbase + swz((16 + lr) * 512 + kk * 64 + lc * 16));
#pragma unroll
                for (int g = 0; g < 5; ++g)
                    acc[1][g] = __builtin_amdgcn_mfma_f32_16x16x32_bf16(a1, Bf[g][kk], acc[1][g], 0, 0, 0);
            }
        }
        __syncthreads();

#pragma unroll
        for (int mt = 0; mt < 2; ++mt)
#pragma unroll
            for (int r = 0; r < 4; ++r) {
                int j = mt * 16 + lc * 4 + r;
                if (j >= nl) continue;
                int row  = tb + loc0 + j;
                int lrow = tb + cloc0 + 2 * j;
                float cl = (float)c_ws[lrow * HH + ee];
                float cr = (float)c_ws[lrow * HH + HH + ee];
                float hv, cv;
                GATES5(acc[mt][0][r] + bi, acc[mt][1][r] + bo, acc[mt][2][r] + bu,
                       acc[mt][3][r] + bl, acc[mt][4][r] + br, cl, cr, hv, cv);
                h_g[row * HH + ee]  = hv;
                c_ws[row * HH + ee] = (half_t)cv;
                *(unsigned short*)(hb + obase + swz(j * 256 + ee * 2)) = f2bf(hv);
            }
    }
}

extern "C" void kernel_launch(void* const* d_in, const int* in_sizes, int n_in,
                              void* d_out, int out_size, void* d_ws, size_t ws_size,
                              hipStream_t stream)
{
    const float* iou   = (const float*)d_in[0];
    const float* c_in  = (const float*)d_in[2];
    const float* W_iou = (const float*)d_in[3];
    const float* b_iou = (const float*)d_in[4];
    const float* W_f   = (const float*)d_in[5];
    const float* b_f   = (const float*)d_in[6];
    float* h_out = (float*)d_out;
    half_t* c_ws = (half_t*)d_ws;                                                       // 67 MiB f16 c
    unsigned short* h_bf = (unsigned short*)((char*)d_ws + (size_t)72 * 1024 * 1024);   // 67 MiB bf16 h

    conv_k<<<160, 256, 0, stream>>>(W_iou, W_f);
    leaf14_k<<<2048, TPB, 0, stream>>>(iou, c_in, b_iou, b_f, h_out, c_ws, h_bf);   // leaves + l=14
    for (int l = 13; l >= 7; --l) {
        int blocks = (4 << l) / 32;
        level_k<<<blocks, TPB, 0, stream>>>(l, b_iou, b_f, h_out, c_ws, h_bf);
    }
    solo_k<<<4, TPB, 0, stream>>>(b_iou, b_f, h_out, c_ws, h_bf);                   // l=6..0
}

// Round 23
// 326.928 us; speedup vs baseline: 1.2005x; 1.0348x over previous
//
#include <hip/hip_runtime.h>

#define HH   128
#define H2   256
#define H3   384
#define NPT  65535      // nodes per tree (2^16 - 1)
#define TPB  512

typedef __bf16    bf16x8 __attribute__((ext_vector_type(8)));
typedef float     f32x4  __attribute__((ext_vector_type(4)));
typedef _Float16  f16x4  __attribute__((ext_vector_type(4)));
typedef _Float16  half_t;

__device__ unsigned short Wb_g[640 * 256];   // bf16 [row=output col j][k]; j<384: W_iou, else W_f

__device__ __forceinline__ float fsig(float x)  { return 1.0f / (1.0f + __expf(-x)); }
__device__ __forceinline__ float ftanh(float x) { return 1.0f - 2.0f / (__expf(2.0f * x) + 1.0f); }
__device__ __forceinline__ unsigned short f2bf(float f) {   // RNE fp32->bf16
    unsigned u = __float_as_uint(f);
    u += 0x7fffu + ((u >> 16) & 1u);
    return (unsigned short)(u >> 16);
}
__device__ __forceinline__ int swz(int off) { return off ^ (((off >> 9) & 7) << 4); }

// ---------------- weight convert ----------------
__global__ __launch_bounds__(256) void conv_k(const float* __restrict__ W_iou,
                                              const float* __restrict__ W_f)
{
    int t    = blockIdx.x * 256 + threadIdx.x;
    int base = t * 4;
    int j = base >> 8, k = base & 255;
    const float* src = (j < H3) ? (W_iou + j * H2 + k)
                                : (W_f + (j - H3) * H2 + k);
    float4 v = *(const float4*)src;
    ushort4 p;
    p.x = f2bf(v.x); p.y = f2bf(v.y); p.z = f2bf(v.z); p.w = f2bf(v.w);
    *(ushort4*)(Wb_g + base) = p;
}

#define GATES5(PI, PO, PU, PL, PR, CL, CR, HV, CV) \
    { CV = fsig(PI) * ftanh(PU) + fsig(PL) * (CL) + fsig(PR) * (CR); \
      HV = fsig(PO) * ftanh(CV); }

// ---------------- fused leaf + l=14 (R20 exact) ----------------
__global__ __launch_bounds__(TPB, 4) void leaf14_k(
    const float* __restrict__ iou, const float* __restrict__ c_in,
    const float* __restrict__ b_iou, const float* __restrict__ b_f,
    float* __restrict__ h_g, half_t* __restrict__ c_ws,
    unsigned short* __restrict__ h_bf)
{
    __shared__ __align__(16) unsigned short A_lds[32 * H2];   // 16 KB: h of 64 leaves, A-layout
    __shared__ __align__(16) half_t         C_lds[64 * HH];   // 16 KB: c of 64 leaves

    const int tid = threadIdx.x;
    const int w  = tid >> 6;
    const int lr = tid & 15;
    const int lc = (tid & 63) >> 4;
    const int ee = w * 16 + lr;
    const int nb = gridDim.x;
    const int bs = (blockIdx.x & 7) * (nb >> 3) + (blockIdx.x >> 3);   // XCD-chunked
    const int node0 = bs * 32;
    const int tree  = node0 >> 14;
    const int lbase = tree * NPT + 32767 + 2 * (node0 & 16383);   // first leaf row

#pragma unroll
    for (int it = 0; it < 4; ++it) {
        int p   = tid + TPB * it;
        int row = p >> 5;            // 0..63
        int e4  = p & 31;
        int grow = lbase + row;
        const float* ip = iou + (size_t)grow * H3 + e4 * 4;
        f32x4 vi = __builtin_nontemporal_load((const f32x4*)(ip));
        f32x4 vo = __builtin_nontemporal_load((const f32x4*)(ip + HH));
        f32x4 vu = __builtin_nontemporal_load((const f32x4*)(ip + 2 * HH));
        f32x4 vc = __builtin_nontemporal_load((const f32x4*)(c_in + (size_t)grow * HH + e4 * 4));
        float4 bi4 = *(const float4*)(b_iou + e4 * 4);
        float4 bo4 = *(const float4*)(b_iou + HH + e4 * 4);
        float4 bu4 = *(const float4*)(b_iou + 2 * HH + e4 * 4);

        f32x4 hn, cn;
#define DOL(X) { float iv = fsig(vi.X + bi4.X); float ov = fsig(vo.X + bo4.X); \
                 float uv = ftanh(vu.X + bu4.X); float cv = iv * uv + vc.X;    \
                 cn.X = cv; hn.X = ov * ftanh(cv); }
        DOL(x) DOL(y) DOL(z) DOL(w)
#undef DOL
        __builtin_nontemporal_store(hn, (f32x4*)(h_g + (size_t)grow * HH + e4 * 4));
        f16x4 cf; cf.x = (half_t)cn.x; cf.y = (half_t)cn.y;
        cf.z = (half_t)cn.z; cf.w = (half_t)cn.w;
        *(f16x4*)(C_lds + row * HH + e4 * 4) = cf;
        int m = row >> 1, half = row & 1;
        uint2 pk;
        pk.x = (unsigned)f2bf(hn.x) | ((unsigned)f2bf(hn.y) << 16);
        pk.y = (unsigned)f2bf(hn.z) | ((unsigned)f2bf(hn.w) << 16);
        int byte = (m * 512 + half * 256 + e4 * 8) ^ ((m & 7) << 4);
        *(uint2*)((char*)A_lds + byte) = pk;
    }
    __syncthreads();

    f32x4 acc[2][5] = {};
    const unsigned short* Wp = Wb_g + ee * H2 + lc * 8;
#pragma unroll
    for (int kk = 0; kk < 8; ++kk) {
        bf16x8 a0 = *(const bf16x8*)((const char*)A_lds + swz(lr * 512 + kk * 64 + lc * 16));
        bf16x8 a1 = *(const bf16x8*)((const char*)A_lds + swz((16 + lr) * 512 + kk * 64 + lc * 16));
#pragma unroll
        for (int g = 0; g < 5; ++g) {
            bf16x8 b = *(const bf16x8*)(Wp + g * HH * H2 + kk * 32);
            acc[0][g] = __builtin_amdgcn_mfma_f32_16x16x32_bf16(a0, b, acc[0][g], 0, 0, 0);
            acc[1][g] = __builtin_amdgcn_mfma_f32_16x16x32_bf16(a1, b, acc[1][g], 0, 0, 0);
        }
    }

    const float bi = b_iou[ee], bo = b_iou[HH + ee], bu = b_iou[2 * HH + ee];
    const float bl = b_f[ee],   br = b_f[HH + ee];
#pragma unroll
    for (int mt = 0; mt < 2; ++mt)
#pragma unroll
        for (int r = 0; r < 4; ++r) {
            int q    = mt * 16 + lc * 4 + r;
            int node = node0 + q;
            int base = tree * NPT + 16383 + (node & 16383);
            int o    = base * HH + ee;
            float cl = (float)C_lds[(2 * q) * HH + ee];
            float cr = (float)C_lds[(2 * q + 1) * HH + ee];
            float hv, cv;
            GATES5(acc[mt][0][r] + bi, acc[mt][1][r] + bo, acc[mt][2][r] + bu,
                   acc[mt][3][r] + bl, acc[mt][4][r] + br, cl, cr, hv, cv);
            __builtin_nontemporal_store(hv, h_g + o);
            c_ws[o] = (half_t)cv;
            h_bf[o] = f2bf(hv);
        }
}

// ---------------- internal level (R20 exact): 32-node tile, l = 13..11 ----------------
__global__ __launch_bounds__(TPB, 4) void level_k(
    int lvl,
    const float* __restrict__ b_iou, const float* __restrict__ b_f,
    float* __restrict__ h_g, half_t* __restrict__ c_ws,
    unsigned short* __restrict__ h_bf)
{
    __shared__ __align__(16) unsigned short A_lds[32 * H2];

    const int tid = threadIdx.x;
    const int w  = tid >> 6;
    const int lr = tid & 15;
    const int lc = (tid & 63) >> 4;
    const int ee = w * 16 + lr;
    const int nb = gridDim.x;
    const int bs = (nb >= 8) ? ((blockIdx.x & 7) * (nb >> 3) + (blockIdx.x >> 3))
                             : blockIdx.x;
    const int node0 = bs * 32;
    const int loc0  = (1 << lvl) - 1;
    const int lmask = loc0;

#pragma unroll
    for (int it = 0; it < 2; ++it) {
        int item = tid + TPB * it;
        int m = item >> 5, u = item & 31;
        int node = node0 + m;
        int tree = node >> lvl;
        int loc  = loc0 + (node & lmask);
        int coff = (tree * NPT + 2 * loc + 1 + (u >> 4)) * HH + (u & 15) * 8;
        uint4 v = *(const uint4*)(h_bf + coff);
        *(uint4*)((char*)A_lds + swz(m * 512 + u * 16)) = v;
    }
    __syncthreads();

    int   rofs[2][4];
    float clv[2][4], crv[2][4];
#pragma unroll
    for (int mt = 0; mt < 2; ++mt)
#pragma unroll
        for (int r = 0; r < 4; ++r) {
            int node = node0 + mt * 16 + lc * 4 + r;
            int tree = node >> lvl;
            int loc  = loc0 + (node & lmask);
            int base = tree * NPT + loc;
            int lrow = base + loc + 1;
            rofs[mt][r] = base * HH + ee;
            clv[mt][r] = (float)c_ws[lrow * HH + ee];
            crv[mt][r] = (float)c_ws[lrow * HH + HH + ee];
        }

    f32x4 acc[2][5] = {};
    const unsigned short* Wp = Wb_g + ee * H2 + lc * 8;
#pragma unroll
    for (int kk = 0; kk < 8; ++kk) {
        bf16x8 a0 = *(const bf16x8*)((const char*)A_lds + swz(lr * 512 + kk * 64 + lc * 16));
        bf16x8 a1 = *(const bf16x8*)((const char*)A_lds + swz((16 + lr) * 512 + kk * 64 + lc * 16));
#pragma unroll
        for (int g = 0; g < 5; ++g) {
            bf16x8 b = *(const bf16x8*)(Wp + g * HH * H2 + kk * 32);
            acc[0][g] = __builtin_amdgcn_mfma_f32_16x16x32_bf16(a0, b, acc[0][g], 0, 0, 0);
            acc[1][g] = __builtin_amdgcn_mfma_f32_16x16x32_bf16(a1, b, acc[1][g], 0, 0, 0);
        }
    }

    const float bi = b_iou[ee], bo = b_iou[HH + ee], bu = b_iou[2 * HH + ee];
    const float bl = b_f[ee],   br = b_f[HH + ee];
#pragma unroll
    for (int mt = 0; mt < 2; ++mt)
#pragma unroll
        for (int r = 0; r < 4; ++r) {
            float hv, cv;
            GATES5(acc[mt][0][r] + bi, acc[mt][1][r] + bo, acc[mt][2][r] + bu,
                   acc[mt][3][r] + bl, acc[mt][4][r] + br, clv[mt][r], crv[mt][r], hv, cv);
            int o = rofs[mt][r];
            __builtin_nontemporal_store(hv, h_g + o);
            c_ws[o] = (half_t)cv;
            h_bf[o] = f2bf(hv);
        }
}

// ---------------- fused l=10,9,8,7: 128 blocks, subtree-affine, LDS-chained ----------------
// Block b owns 32 l=10 nodes [32b,32b+32), their 16 l=9 parents, 8 l=8, 4 l=7.
// Only l=10 stages from global (l=11 h_bf); parents read children h/c from LDS.
// Only l=7 writes h_bf/c_ws (solo's input); l=10..8 write h_g + LDS only.
__global__ __launch_bounds__(TPB, 2) void quad_k(
    const float* __restrict__ b_iou, const float* __restrict__ b_f,
    float* __restrict__ h_g, half_t* __restrict__ c_ws,
    unsigned short* __restrict__ h_bf)
{
    __shared__ __align__(16) unsigned short A10[32 * H2];  // 16 KB: l=11 h staged
    __shared__ __align__(16) unsigned short A9[16 * H2];   // 8 KB: l=10 h out (A-layout)
    __shared__ __align__(16) unsigned short A8[16 * H2];   // 8 KB: l=9 h out (rows 8+ zero)
    __shared__ __align__(16) unsigned short A7[16 * H2];   // 8 KB: l=8 h out (rows 4+ zero)
    __shared__ __align__(16) half_t C10[32 * HH];          // 8 KB
    __shared__ __align__(16) half_t C9[16 * HH];           // 4 KB
    __shared__ __align__(16) half_t C8[8 * HH];            // 2 KB

    const int tid = threadIdx.x;
    const int w  = tid >> 6;
    const int lr = tid & 15;
    const int lc = (tid & 63) >> 4;
    const int ee = w * 16 + lr;
    const int b  = blockIdx.x;
    const float bi = b_iou[ee], bo = b_iou[HH + ee], bu = b_iou[2 * HH + ee];
    const float bl = b_f[ee],   br = b_f[HH + ee];
    const unsigned short* Wp = Wb_g + ee * H2 + lc * 8;

    // zero A8/A7 (pad rows must be 0) + stage l=10 children (l=11 h_bf)
    {
        uint4 z = make_uint4(0u, 0u, 0u, 0u);
        *(uint4*)((char*)A8 + tid * 16) = z;
        *(uint4*)((char*)A7 + tid * 16) = z;
    }
#pragma unroll
    for (int it = 0; it < 2; ++it) {
        int item = tid + TPB * it;
        int m = item >> 5, u = item & 31;
        int node = b * 32 + m;
        int tree = node >> 10;
        int loc  = 1023 + (node & 1023);
        int coff = (tree * NPT + 2 * loc + 1 + (u >> 4)) * HH + (u & 15) * 8;
        uint4 v = *(const uint4*)(h_bf + coff);
        *(uint4*)((char*)A10 + swz(m * 512 + u * 16)) = v;
    }
    __syncthreads();

    // ---- l=10: 32-node tile; c children from global (l=11 c_ws) ----
    {
        f32x4 acc[2][5] = {};
#pragma unroll
        for (int kk = 0; kk < 8; ++kk) {
            bf16x8 a0 = *(const bf16x8*)((const char*)A10 + swz(lr * 512 + kk * 64 + lc * 16));
            bf16x8 a1 = *(const bf16x8*)((const char*)A10 + swz((16 + lr) * 512 + kk * 64 + lc * 16));
#pragma unroll
            for (int g = 0; g < 5; ++g) {
                bf16x8 bb = *(const bf16x8*)(Wp + g * HH * H2 + kk * 32);
                acc[0][g] = __builtin_amdgcn_mfma_f32_16x16x32_bf16(a0, bb, acc[0][g], 0, 0, 0);
                acc[1][g] = __builtin_amdgcn_mfma_f32_16x16x32_bf16(a1, bb, acc[1][g], 0, 0, 0);
            }
        }
#pragma unroll
        for (int mt = 0; mt < 2; ++mt)
#pragma unroll
            for (int r = 0; r < 4; ++r) {
                int q    = mt * 16 + lc * 4 + r;          // 0..31
                int node = b * 32 + q;
                int tree = node >> 10;
                int loc  = 1023 + (node & 1023);
                int base = tree * NPT + loc;
                int lrow = base + loc + 1;
                float cl = (float)c_ws[lrow * HH + ee];
                float cr = (float)c_ws[lrow * HH + HH + ee];
                float hv, cv;
                GATES5(acc[mt][0][r] + bi, acc[mt][1][r] + bo, acc[mt][2][r] + bu,
                       acc[mt][3][r] + bl, acc[mt][4][r] + br, cl, cr, hv, cv);
                __builtin_nontemporal_store(hv, h_g + base * HH + ee);
                int m = q >> 1, half = q & 1;
                *(unsigned short*)((char*)A9 + ((m * 512 + half * 256 + ee * 2) ^ ((m & 7) << 4))) = f2bf(hv);
                C10[q * HH + ee] = (half_t)cv;
            }
    }
    __syncthreads();

    // ---- l=9: 16 nodes; children entirely in LDS ----
    {
        f32x4 acc[5] = {};
#pragma unroll
        for (int kk = 0; kk < 8; ++kk) {
            bf16x8 a0 = *(const bf16x8*)((const char*)A9 + swz(lr * 512 + kk * 64 + lc * 16));
#pragma unroll
            for (int g = 0; g < 5; ++g)
                acc[g] = __builtin_amdgcn_mfma_f32_16x16x32_bf16(a0,
                          *(const bf16x8*)(Wp + g * HH * H2 + kk * 32), acc[g], 0, 0, 0);
        }
#pragma unroll
        for (int r = 0; r < 4; ++r) {
            int j    = lc * 4 + r;                        // 0..15
            int node = b * 16 + j;
            int tree = node >> 9;
            int loc  = 511 + (node & 511);
            int base = tree * NPT + loc;
            float cl = (float)C10[(2 * j) * HH + ee];
            float cr = (float)C10[(2 * j + 1) * HH + ee];
            float hv, cv;
            GATES5(acc[0][r] + bi, acc[1][r] + bo, acc[2][r] + bu,
                   acc[3][r] + bl, acc[4][r] + br, cl, cr, hv, cv);
            __builtin_nontemporal_store(hv, h_g + base * HH + ee);
            int m = j >> 1, half = j & 1;
            *(unsigned short*)((char*)A8 + ((m * 512 + half * 256 + ee * 2) ^ ((m & 7) << 4))) = f2bf(hv);
            C9[j * HH + ee] = (half_t)cv;
        }
    }
    __syncthreads();

    // ---- l=8: 8 nodes (tile rows 8..15 are zero-padded) ----
    {
        f32x4 acc[5] = {};
#pragma unroll
        for (int kk = 0; kk < 8; ++kk) {
            bf16x8 a0 = *(const bf16x8*)((const char*)A8 + swz(lr * 512 + kk * 64 + lc * 16));
#pragma unroll
            for (int g = 0; g < 5; ++g)
                acc[g] = __builtin_amdgcn_mfma_f32_16x16x32_bf16(a0,
                          *(const bf16x8*)(Wp + g * HH * H2 + kk * 32), acc[g], 0, 0, 0);
        }
#pragma unroll
        for (int r = 0; r < 4; ++r) {
            int j = lc * 4 + r;
            if (j < 8) {
                int node = b * 8 + j;
                int tree = node >> 8;
                int loc  = 255 + (node & 255);
                int base = tree * NPT + loc;
                float cl = (float)C9[(2 * j) * HH + ee];
                float cr = (float)C9[(2 * j + 1) * HH + ee];
                float hv, cv;
                GATES5(acc[0][r] + bi, acc[1][r] + bo, acc[2][r] + bu,
                       acc[3][r] + bl, acc[4][r] + br, cl, cr, hv, cv);
                __builtin_nontemporal_store(hv, h_g + base * HH + ee);
                int m = j >> 1, half = j & 1;
                *(unsigned short*)((char*)A7 + ((m * 512 + half * 256 + ee * 2) ^ ((m & 7) << 4))) = f2bf(hv);
                C8[j * HH + ee] = (half_t)cv;
            }
        }
    }
    __syncthreads();

    // ---- l=7: 4 nodes (tile rows 4..15 zero); writes h_bf/c_ws for solo ----
    {
        f32x4 acc[5] = {};
#pragma unroll
        for (int kk = 0; kk < 8; ++kk) {
            bf16x8 a0 = *(const bf16x8*)((const char*)A7 + swz(lr * 512 + kk * 64 + lc * 16));
#pragma unroll
            for (int g = 0; g < 5; ++g)
                acc[g] = __builtin_amdgcn_mfma_f32_16x16x32_bf16(a0,
                          *(const bf16x8*)(Wp + g * HH * H2 + kk * 32), acc[g], 0, 0, 0);
        }
#pragma unroll
        for (int r = 0; r < 4; ++r) {
            int j = lc * 4 + r;
            if (j < 4) {
                int node = b * 4 + j;
                int tree = node >> 7;
                int loc  = 127 + (node & 127);
                int base = tree * NPT + loc;
                int o    = base * HH + ee;
                float cl = (float)C8[(2 * j) * HH + ee];
                float cr = (float)C8[(2 * j + 1) * HH + ee];
                float hv, cv;
                GATES5(acc[0][r] + bi, acc[1][r] + bo, acc[2][r] + bu,
                       acc[3][r] + bl, acc[4][r] + br, cl, cr, hv, cv);
                h_g[o]  = hv;
                c_ws[o] = (half_t)cv;
                h_bf[o] = f2bf(hv);
            }
        }
    }
}

// ---------------- solo tail l=6..0 (R22 exact) ----------------
__global__ __launch_bounds__(TPB, 2) void solo_k(
    const float* __restrict__ b_iou, const float* __restrict__ b_f,
    float* __restrict__ h_g, half_t* __restrict__ c_ws,
    const unsigned short* __restrict__ h_bf)
{
    __shared__ __align__(16) unsigned char hb[49152];

    const int tid = threadIdx.x;
    const int w = tid >> 6, lr = tid & 15, lc = (tid & 63) >> 4;
    const int ee = w * 16 + lr;
    const int tb = blockIdx.x * NPT;
    const float bi = b_iou[ee], bo = b_iou[HH + ee], bu = b_iou[2 * HH + ee];
    const float bl = b_f[ee],   br = b_f[HH + ee];

    bf16x8 Bf[5][8];
    const unsigned short* Wp = Wb_g + ee * H2 + lc * 8;
#pragma unroll
    for (int g = 0; g < 5; ++g)
#pragma unroll
        for (int kk = 0; kk < 8; ++kk)
            Bf[g][kk] = *(const bf16x8*)(Wp + g * HH * H2 + kk * 32);

    // ---- stage l=7 h: 128 rows x 256B = 32 KB (rows tb+127 .. tb+254) ----
#pragma unroll
    for (int it = 0; it < 4; ++it) {
        int p = tid + TPB * it;            // 2048 chunks of 16B
        int cc = p >> 4, q = p & 15;
        uint4 v = *(const uint4*)(h_bf + (tb + 127 + cc) * HH + q * 8);
        *(uint4*)(hb + swz(p * 16)) = v;
    }
    __syncthreads();

    // ---- l=6: 64 nodes = two 32-node tiles; children h from LDS, c from global ----
#pragma unroll 1
    for (int tt = 0; tt < 2; ++tt) {
        f32x4 acc[2][5] = {};
#pragma unroll
        for (int kk = 0; kk < 8; ++kk) {
            bf16x8 a0 = *(const bf16x8*)(hb + swz(tt * 16384 + lr * 512 + kk * 64 + lc * 16));
            bf16x8 a1 = *(const bf16x8*)(hb + swz(tt * 16384 + (16 + lr) * 512 + kk * 64 + lc * 16));
#pragma unroll
            for (int g = 0; g < 5; ++g) {
                acc[0][g] = __builtin_amdgcn_mfma_f32_16x16x32_bf16(a0, Bf[g][kk], acc[0][g], 0, 0, 0);
                acc[1][g] = __builtin_amdgcn_mfma_f32_16x16x32_bf16(a1, Bf[g][kk], acc[1][g], 0, 0, 0);
            }
        }
#pragma unroll
        for (int mt = 0; mt < 2; ++mt)
#pragma unroll
            for (int r = 0; r < 4; ++r) {
                int j    = tt * 32 + mt * 16 + lc * 4 + r;   // l=6 node 0..63
                int row  = tb + 63 + j;
                int lrow = tb + 127 + 2 * j;
                float cl = (float)c_ws[lrow * HH + ee];
                float cr = (float)c_ws[lrow * HH + HH + ee];
                float hv, cv;
                GATES5(acc[mt][0][r] + bi, acc[mt][1][r] + bo, acc[mt][2][r] + bu,
                       acc[mt][3][r] + bl, acc[mt][4][r] + br, cl, cr, hv, cv);
                h_g[row * HH + ee]  = hv;
                c_ws[row * HH + ee] = (half_t)cv;
                *(unsigned short*)(hb + 32768 + swz(j * 256 + ee * 2)) = f2bf(hv);
            }
    }

    // ---- l=5..0: ping-pong (l=5 reads the 32K l=6-out region) ----
#pragma unroll 1
    for (int l = 5; l >= 0; --l) {
        const int nl     = 1 << l;
        const int loc0   = nl - 1;
        const int cloc0  = 2 * nl - 1;
        const int cbase  = (l == 5) ? 32768 : ((l & 1) ? 16384 : 0);
        const int obase  = (l == 5) ? 0 : (((l & 1) ? 16384 : 0) ^ 16384);
        const bool mt1   = (nl > 16);

        __syncthreads();

        f32x4 acc[2][5] = {};
#pragma unroll
        for (int kk = 0; kk < 8; ++kk) {
            bf16x8 a0 = *(const bf16x8*)(hb + cbase + swz(lr * 512 + kk * 64 + lc * 16));
#pragma unroll
            for (int g = 0; g < 5; ++g)
                acc[0][g] = __builtin_amdgcn_mfma_f32_16x16x32_bf16(a0, Bf[g][kk], acc[0][g], 0, 0, 0);
            if (mt1) {
                bf16x8 a1 = *(const bf16x8*)(hb + cbase + swz((16 + lr) * 512 + kk * 64 + lc * 16));
#pragma unroll
                for (int g = 0; g < 5; ++g)
                    acc[1][g] = __builtin_amdgcn_mfma_f32_16x16x32_bf16(a1, Bf[g][kk], acc[1][g], 0, 0, 0);
            }
        }
        __syncthreads();

#pragma unroll
        for (int mt = 0; mt < 2; ++mt)
#pragma unroll
            for (int r = 0; r < 4; ++r) {
                int j = mt * 16 + lc * 4 + r;
                if (j >= nl) continue;
                int row  = tb + loc0 + j;
                int lrow = tb + cloc0 + 2 * j;
                float cl = (float)c_ws[lrow * HH + ee];
                float cr = (float)c_ws[lrow * HH + HH + ee];
                float hv, cv;
                GATES5(acc[mt][0][r] + bi, acc[mt][1][r] + bo, acc[mt][2][r] + bu,
                       acc[mt][3][r] + bl, acc[mt][4][r] + br, cl, cr, hv, cv);
                h_g[row * HH + ee]  = hv;
                c_ws[row * HH + ee] = (half_t)cv;
                *(unsigned short*)(hb + obase + swz(j * 256 + ee * 2)) = f2bf(hv);
            }
    }
}

extern "C" void kernel_launch(void* const* d_in, const int* in_sizes, int n_in,
                              void* d_out, int out_size, void* d_ws, size_t ws_size,
                              hipStream_t stream)
{
    const float* iou   = (const float*)d_in[0];
    const float* c_in  = (const float*)d_in[2];
    const float* W_iou = (const float*)d_in[3];
    const float* b_iou = (const float*)d_in[4];
    const float* W_f   = (const float*)d_in[5];
    const float* b_f   = (const float*)d_in[6];
    float* h_out = (float*)d_out;
    half_t* c_ws = (half_t*)d_ws;                                                       // 67 MiB f16 c
    unsigned short* h_bf = (unsigned short*)((char*)d_ws + (size_t)72 * 1024 * 1024);   // 67 MiB bf16 h

    conv_k<<<160, 256, 0, stream>>>(W_iou, W_f);
    leaf14_k<<<2048, TPB, 0, stream>>>(iou, c_in, b_iou, b_f, h_out, c_ws, h_bf);   // leaves + l=14
    for (int l = 13; l >= 11; --l) {
        int blocks = (4 << l) / 32;
        level_k<<<blocks, TPB, 0, stream>>>(l, b_iou, b_f, h_out, c_ws, h_bf);
    }
    quad_k<<<128, TPB, 0, stream>>>(b_iou, b_f, h_out, c_ws, h_bf);                 // l=10..7
    solo_k<<<4, TPB, 0, stream>>>(b_iou, b_f, h_out, c_ws, h_bf);                   // l=6..0
}

// Round 24
// 321.592 us; speedup vs baseline: 1.2204x; 1.0166x over previous
//
#include <hip/hip_runtime.h>

#define HH   128
#define H2   256
#define H3   384
#define NPT  65535      // nodes per tree (2^16 - 1)
#define TPB  512

typedef __bf16    bf16x8 __attribute__((ext_vector_type(8)));
typedef float     f32x4  __attribute__((ext_vector_type(4)));
typedef _Float16  f16x4  __attribute__((ext_vector_type(4)));
typedef _Float16  half_t;

__device__ unsigned short Wb_g[640 * 256];   // bf16 [row=output col j][k]; j<384: W_iou, else W_f

__device__ __forceinline__ float fsig(float x)  { return 1.0f / (1.0f + __expf(-x)); }
__device__ __forceinline__ float ftanh(float x) { return 1.0f - 2.0f / (__expf(2.0f * x) + 1.0f); }
__device__ __forceinline__ unsigned short f2bf(float f) {   // RNE fp32->bf16
    unsigned u = __float_as_uint(f);
    u += 0x7fffu + ((u >> 16) & 1u);
    return (unsigned short)(u >> 16);
}
__device__ __forceinline__ int swz(int off) { return off ^ (((off >> 9) & 7) << 4); }

// ---------------- weight convert ----------------
__global__ __launch_bounds__(256) void conv_k(const float* __restrict__ W_iou,
                                              const float* __restrict__ W_f)
{
    int t    = blockIdx.x * 256 + threadIdx.x;
    int base = t * 4;
    int j = base >> 8, k = base & 255;
    const float* src = (j < H3) ? (W_iou + j * H2 + k)
                                : (W_f + (j - H3) * H2 + k);
    float4 v = *(const float4*)src;
    ushort4 p;
    p.x = f2bf(v.x); p.y = f2bf(v.y); p.z = f2bf(v.z); p.w = f2bf(v.w);
    *(ushort4*)(Wb_g + base) = p;
}

#define GATES5(PI, PO, PU, PL, PR, CL, CR, HV, CV) \
    { CV = fsig(PI) * ftanh(PU) + fsig(PL) * (CL) + fsig(PR) * (CR); \
      HV = fsig(PO) * ftanh(CV); }

// ---------------- fused leaf + l=14 (R20 exact) ----------------
__global__ __launch_bounds__(TPB, 4) void leaf14_k(
    const float* __restrict__ iou, const float* __restrict__ c_in,
    const float* __restrict__ b_iou, const float* __restrict__ b_f,
    float* __restrict__ h_g, half_t* __restrict__ c_ws,
    unsigned short* __restrict__ h_bf)
{
    __shared__ __align__(16) unsigned short A_lds[32 * H2];   // 16 KB: h of 64 leaves, A-layout
    __shared__ __align__(16) half_t         C_lds[64 * HH];   // 16 KB: c of 64 leaves

    const int tid = threadIdx.x;
    const int w  = tid >> 6;
    const int lr = tid & 15;
    const int lc = (tid & 63) >> 4;
    const int ee = w * 16 + lr;
    const int nb = gridDim.x;
    const int bs = (blockIdx.x & 7) * (nb >> 3) + (blockIdx.x >> 3);   // XCD-chunked
    const int node0 = bs * 32;
    const int tree  = node0 >> 14;
    const int lbase = tree * NPT + 32767 + 2 * (node0 & 16383);   // first leaf row

#pragma unroll
    for (int it = 0; it < 4; ++it) {
        int p   = tid + TPB * it;
        int row = p >> 5;            // 0..63
        int e4  = p & 31;
        int grow = lbase + row;
        const float* ip = iou + (size_t)grow * H3 + e4 * 4;
        f32x4 vi = __builtin_nontemporal_load((const f32x4*)(ip));
        f32x4 vo = __builtin_nontemporal_load((const f32x4*)(ip + HH));
        f32x4 vu = __builtin_nontemporal_load((const f32x4*)(ip + 2 * HH));
        f32x4 vc = __builtin_nontemporal_load((const f32x4*)(c_in + (size_t)grow * HH + e4 * 4));
        float4 bi4 = *(const float4*)(b_iou + e4 * 4);
        float4 bo4 = *(const float4*)(b_iou + HH + e4 * 4);
        float4 bu4 = *(const float4*)(b_iou + 2 * HH + e4 * 4);

        f32x4 hn, cn;
#define DOL(X) { float iv = fsig(vi.X + bi4.X); float ov = fsig(vo.X + bo4.X); \
                 float uv = ftanh(vu.X + bu4.X); float cv = iv * uv + vc.X;    \
                 cn.X = cv; hn.X = ov * ftanh(cv); }
        DOL(x) DOL(y) DOL(z) DOL(w)
#undef DOL
        __builtin_nontemporal_store(hn, (f32x4*)(h_g + (size_t)grow * HH + e4 * 4));
        f16x4 cf; cf.x = (half_t)cn.x; cf.y = (half_t)cn.y;
        cf.z = (half_t)cn.z; cf.w = (half_t)cn.w;
        *(f16x4*)(C_lds + row * HH + e4 * 4) = cf;
        int m = row >> 1, half = row & 1;
        uint2 pk;
        pk.x = (unsigned)f2bf(hn.x) | ((unsigned)f2bf(hn.y) << 16);
        pk.y = (unsigned)f2bf(hn.z) | ((unsigned)f2bf(hn.w) << 16);
        int byte = (m * 512 + half * 256 + e4 * 8) ^ ((m & 7) << 4);
        *(uint2*)((char*)A_lds + byte) = pk;
    }
    __syncthreads();

    f32x4 acc[2][5] = {};
    const unsigned short* Wp = Wb_g + ee * H2 + lc * 8;
#pragma unroll
    for (int kk = 0; kk < 8; ++kk) {
        bf16x8 a0 = *(const bf16x8*)((const char*)A_lds + swz(lr * 512 + kk * 64 + lc * 16));
        bf16x8 a1 = *(const bf16x8*)((const char*)A_lds + swz((16 + lr) * 512 + kk * 64 + lc * 16));
#pragma unroll
        for (int g = 0; g < 5; ++g) {
            bf16x8 b = *(const bf16x8*)(Wp + g * HH * H2 + kk * 32);
            acc[0][g] = __builtin_amdgcn_mfma_f32_16x16x32_bf16(a0, b, acc[0][g], 0, 0, 0);
            acc[1][g] = __builtin_amdgcn_mfma_f32_16x16x32_bf16(a1, b, acc[1][g], 0, 0, 0);
        }
    }

    const float bi = b_iou[ee], bo = b_iou[HH + ee], bu = b_iou[2 * HH + ee];
    const float bl = b_f[ee],   br = b_f[HH + ee];
#pragma unroll
    for (int mt = 0; mt < 2; ++mt)
#pragma unroll
        for (int r = 0; r < 4; ++r) {
            int q    = mt * 16 + lc * 4 + r;
            int node = node0 + q;
            int base = tree * NPT + 16383 + (node & 16383);
            int o    = base * HH + ee;
            float cl = (float)C_lds[(2 * q) * HH + ee];
            float cr = (float)C_lds[(2 * q + 1) * HH + ee];
            float hv, cv;
            GATES5(acc[mt][0][r] + bi, acc[mt][1][r] + bo, acc[mt][2][r] + bu,
                   acc[mt][3][r] + bl, acc[mt][4][r] + br, cl, cr, hv, cv);
            __builtin_nontemporal_store(hv, h_g + o);
            c_ws[o] = (half_t)cv;
            h_bf[o] = f2bf(hv);
        }
}

// ---------------- internal level (R20 exact): 32-node tile, l = 13..12 ----------------
__global__ __launch_bounds__(TPB, 4) void level_k(
    int lvl,
    const float* __restrict__ b_iou, const float* __restrict__ b_f,
    float* __restrict__ h_g, half_t* __restrict__ c_ws,
    unsigned short* __restrict__ h_bf)
{
    __shared__ __align__(16) unsigned short A_lds[32 * H2];

    const int tid = threadIdx.x;
    const int w  = tid >> 6;
    const int lr = tid & 15;
    const int lc = (tid & 63) >> 4;
    const int ee = w * 16 + lr;
    const int nb = gridDim.x;
    const int bs = (nb >= 8) ? ((blockIdx.x & 7) * (nb >> 3) + (blockIdx.x >> 3))
                             : blockIdx.x;
    const int node0 = bs * 32;
    const int loc0  = (1 << lvl) - 1;
    const int lmask = loc0;

#pragma unroll
    for (int it = 0; it < 2; ++it) {
        int item = tid + TPB * it;
        int m = item >> 5, u = item & 31;
        int node = node0 + m;
        int tree = node >> lvl;
        int loc  = loc0 + (node & lmask);
        int coff = (tree * NPT + 2 * loc + 1 + (u >> 4)) * HH + (u & 15) * 8;
        uint4 v = *(const uint4*)(h_bf + coff);
        *(uint4*)((char*)A_lds + swz(m * 512 + u * 16)) = v;
    }
    __syncthreads();

    int   rofs[2][4];
    float clv[2][4], crv[2][4];
#pragma unroll
    for (int mt = 0; mt < 2; ++mt)
#pragma unroll
        for (int r = 0; r < 4; ++r) {
            int node = node0 + mt * 16 + lc * 4 + r;
            int tree = node >> lvl;
            int loc  = loc0 + (node & lmask);
            int base = tree * NPT + loc;
            int lrow = base + loc + 1;
            rofs[mt][r] = base * HH + ee;
            clv[mt][r] = (float)c_ws[lrow * HH + ee];
            crv[mt][r] = (float)c_ws[lrow * HH + HH + ee];
        }

    f32x4 acc[2][5] = {};
    const unsigned short* Wp = Wb_g + ee * H2 + lc * 8;
#pragma unroll
    for (int kk = 0; kk < 8; ++kk) {
        bf16x8 a0 = *(const bf16x8*)((const char*)A_lds + swz(lr * 512 + kk * 64 + lc * 16));
        bf16x8 a1 = *(const bf16x8*)((const char*)A_lds + swz((16 + lr) * 512 + kk * 64 + lc * 16));
#pragma unroll
        for (int g = 0; g < 5; ++g) {
            bf16x8 b = *(const bf16x8*)(Wp + g * HH * H2 + kk * 32);
            acc[0][g] = __builtin_amdgcn_mfma_f32_16x16x32_bf16(a0, b, acc[0][g], 0, 0, 0);
            acc[1][g] = __builtin_amdgcn_mfma_f32_16x16x32_bf16(a1, b, acc[1][g], 0, 0, 0);
        }
    }

    const float bi = b_iou[ee], bo = b_iou[HH + ee], bu = b_iou[2 * HH + ee];
    const float bl = b_f[ee],   br = b_f[HH + ee];
#pragma unroll
    for (int mt = 0; mt < 2; ++mt)
#pragma unroll
        for (int r = 0; r < 4; ++r) {
            float hv, cv;
            GATES5(acc[mt][0][r] + bi, acc[mt][1][r] + bo, acc[mt][2][r] + bu,
                   acc[mt][3][r] + bl, acc[mt][4][r] + br, clv[mt][r], crv[mt][r], hv, cv);
            int o = rofs[mt][r];
            __builtin_nontemporal_store(hv, h_g + o);
            c_ws[o] = (half_t)cv;
            h_bf[o] = f2bf(hv);
        }
}

// ---------------- fused l=11,10,9,8,7: 256 blocks (1/CU), subtree-affine, LDS-chained ----------------
// Block b owns 32 l=11 nodes [32b,32b+32), 16 l=10, 8 l=9, 4 l=8, 2 l=7.
// Only l=11 stages from global (l=12 h_bf) and reads child c from global; everything
// below reads children h AND c from LDS. Only l=7 writes h_bf/c_ws (solo's input).
__global__ __launch_bounds__(TPB, 2) void quint_k(
    const float* __restrict__ b_iou, const float* __restrict__ b_f,
    float* __restrict__ h_g, half_t* __restrict__ c_ws,
    unsigned short* __restrict__ h_bf)
{
    __shared__ __align__(16) unsigned short Astg[32 * H2];  // 16 KB: l=12 h staged
    __shared__ __align__(16) unsigned short A10[16 * H2];   // 8 KB: l=11 h out (16 rows)
    __shared__ __align__(16) unsigned short A9[16 * H2];    // 8 KB: l=10 h out (rows 8+ zero)
    __shared__ __align__(16) unsigned short A8[16 * H2];    // 8 KB: l=9 h out (rows 4+ zero)
    __shared__ __align__(16) unsigned short A7[16 * H2];    // 8 KB: l=8 h out (rows 2+ zero)
    __shared__ __align__(16) half_t C11[32 * HH];           // 8 KB
    __shared__ __align__(16) half_t C10[16 * HH];           // 4 KB
    __shared__ __align__(16) half_t C9[8 * HH];             // 2 KB
    __shared__ __align__(16) half_t C8[4 * HH];             // 1 KB

    const int tid = threadIdx.x;
    const int w  = tid >> 6;
    const int lr = tid & 15;
    const int lc = (tid & 63) >> 4;
    const int ee = w * 16 + lr;
    const int b  = blockIdx.x;
    const float bi = b_iou[ee], bo = b_iou[HH + ee], bu = b_iou[2 * HH + ee];
    const float bl = b_f[ee],   br = b_f[HH + ee];
    const unsigned short* Wp = Wb_g + ee * H2 + lc * 8;

    // zero pad rows of A9/A8/A7 + stage l=11 children (l=12 h_bf)
    {
        uint4 z = make_uint4(0u, 0u, 0u, 0u);
        *(uint4*)((char*)A9 + tid * 16) = z;
        *(uint4*)((char*)A8 + tid * 16) = z;
        *(uint4*)((char*)A7 + tid * 16) = z;
    }
#pragma unroll
    for (int it = 0; it < 2; ++it) {
        int item = tid + TPB * it;
        int m = item >> 5, u = item & 31;
        int node = b * 32 + m;
        int tree = node >> 11;
        int loc  = 2047 + (node & 2047);
        int coff = (tree * NPT + 2 * loc + 1 + (u >> 4)) * HH + (u & 15) * 8;
        uint4 v = *(const uint4*)(h_bf + coff);
        *(uint4*)((char*)Astg + swz(m * 512 + u * 16)) = v;
    }
    __syncthreads();

    // ---- l=11: 32-node tile; c children from global (l=12 c_ws) ----
    {
        f32x4 acc[2][5] = {};
#pragma unroll
        for (int kk = 0; kk < 8; ++kk) {
            bf16x8 a0 = *(const bf16x8*)((const char*)Astg + swz(lr * 512 + kk * 64 + lc * 16));
            bf16x8 a1 = *(const bf16x8*)((const char*)Astg + swz((16 + lr) * 512 + kk * 64 + lc * 16));
#pragma unroll
            for (int g = 0; g < 5; ++g) {
                bf16x8 bb = *(const bf16x8*)(Wp + g * HH * H2 + kk * 32);
                acc[0][g] = __builtin_amdgcn_mfma_f32_16x16x32_bf16(a0, bb, acc[0][g], 0, 0, 0);
                acc[1][g] = __builtin_amdgcn_mfma_f32_16x16x32_bf16(a1, bb, acc[1][g], 0, 0, 0);
            }
        }
#pragma unroll
        for (int mt = 0; mt < 2; ++mt)
#pragma unroll
            for (int r = 0; r < 4; ++r) {
                int q    = mt * 16 + lc * 4 + r;          // 0..31
                int node = b * 32 + q;
                int tree = node >> 11;
                int loc  = 2047 + (node & 2047);
                int base = tree * NPT + loc;
                int lrow = base + loc + 1;
                float cl = (float)c_ws[lrow * HH + ee];
                float cr = (float)c_ws[lrow * HH + HH + ee];
                float hv, cv;
                GATES5(acc[mt][0][r] + bi, acc[mt][1][r] + bo, acc[mt][2][r] + bu,
                       acc[mt][3][r] + bl, acc[mt][4][r] + br, cl, cr, hv, cv);
                __builtin_nontemporal_store(hv, h_g + base * HH + ee);
                int m = q >> 1, half = q & 1;
                *(unsigned short*)((char*)A10 + ((m * 512 + half * 256 + ee * 2) ^ ((m & 7) << 4))) = f2bf(hv);
                C11[q * HH + ee] = (half_t)cv;
            }
    }
    __syncthreads();

    // ---- l=10: 16 nodes; children h/c entirely in LDS ----
    {
        f32x4 acc[5] = {};
#pragma unroll
        for (int kk = 0; kk < 8; ++kk) {
            bf16x8 a0 = *(const bf16x8*)((const char*)A10 + swz(lr * 512 + kk * 64 + lc * 16));
#pragma unroll
            for (int g = 0; g < 5; ++g)
                acc[g] = __builtin_amdgcn_mfma_f32_16x16x32_bf16(a0,
                          *(const bf16x8*)(Wp + g * HH * H2 + kk * 32), acc[g], 0, 0, 0);
        }
#pragma unroll
        for (int r = 0; r < 4; ++r) {
            int j    = lc * 4 + r;                        // 0..15
            int node = b * 16 + j;
            int tree = node >> 10;
            int loc  = 1023 + (node & 1023);
            int base = tree * NPT + loc;
            float cl = (float)C11[(2 * j) * HH + ee];
            float cr = (float)C11[(2 * j + 1) * HH + ee];
            float hv, cv;
            GATES5(acc[0][r] + bi, acc[1][r] + bo, acc[2][r] + bu,
                   acc[3][r] + bl, acc[4][r] + br, cl, cr, hv, cv);
            __builtin_nontemporal_store(hv, h_g + base * HH + ee);
            int m = j >> 1, half = j & 1;
            *(unsigned short*)((char*)A9 + ((m * 512 + half * 256 + ee * 2) ^ ((m & 7) << 4))) = f2bf(hv);
            C10[j * HH + ee] = (half_t)cv;
        }
    }
    __syncthreads();

    // ---- l=9: 8 nodes (rows 8..15 zero) ----
    {
        f32x4 acc[5] = {};
#pragma unroll
        for (int kk = 0; kk < 8; ++kk) {
            bf16x8 a0 = *(const bf16x8*)((const char*)A9 + swz(lr * 512 + kk * 64 + lc * 16));
#pragma unroll
            for (int g = 0; g < 5; ++g)
                acc[g] = __builtin_amdgcn_mfma_f32_16x16x32_bf16(a0,
                          *(const bf16x8*)(Wp + g * HH * H2 + kk * 32), acc[g], 0, 0, 0);
        }
#pragma unroll
        for (int r = 0; r < 4; ++r) {
            int j = lc * 4 + r;
            if (j < 8) {
                int node = b * 8 + j;
                int tree = node >> 9;
                int loc  = 511 + (node & 511);
                int base = tree * NPT + loc;
                float cl = (float)C10[(2 * j) * HH + ee];
                float cr = (float)C10[(2 * j + 1) * HH + ee];
                float hv, cv;
                GATES5(acc[0][r] + bi, acc[1][r] + bo, acc[2][r] + bu,
                       acc[3][r] + bl, acc[4][r] + br, cl, cr, hv, cv);
                __builtin_nontemporal_store(hv, h_g + base * HH + ee);
                int m = j >> 1, half = j & 1;
                *(unsigned short*)((char*)A8 + ((m * 512 + half * 256 + ee * 2) ^ ((m & 7) << 4))) = f2bf(hv);
                C9[j * HH + ee] = (half_t)cv;
            }
        }
    }
    __syncthreads();

    // ---- l=8: 4 nodes (rows 2..15 zero beyond written) ----
    {
        f32x4 acc[5] = {};
#pragma unroll
        for (int kk = 0; kk < 8; ++kk) {
            bf16x8 a0 = *(const bf16x8*)((const char*)A8 + swz(lr * 512 + kk * 64 + lc * 16));
#pragma unroll
            for (int g = 0; g < 5; ++g)
                acc[g] = __builtin_amdgcn_mfma_f32_16x16x32_bf16(a0,
                          *(const bf16x8*)(Wp + g * HH * H2 + kk * 32), acc[g], 0, 0, 0);
        }
#pragma unroll
        for (int r = 0; r < 4; ++r) {
            int j = lc * 4 + r;
            if (j < 4) {
                int node = b * 4 + j;
                int tree = node >> 8;
                int loc  = 255 + (node & 255);
                int base = tree * NPT + loc;
                float cl = (float)C9[(2 * j) * HH + ee];
                float cr = (float)C9[(2 * j + 1) * HH + ee];
                float hv, cv;
                GATES5(acc[0][r] + bi, acc[1][r] + bo, acc[2][r] + bu,
                       acc[3][r] + bl, acc[4][r] + br, cl, cr, hv, cv);
                __builtin_nontemporal_store(hv, h_g + base * HH + ee);
                int m = j >> 1, half = j & 1;
                *(unsigned short*)((char*)A7 + ((m * 512 + half * 256 + ee * 2) ^ ((m & 7) << 4))) = f2bf(hv);
                C8[j * HH + ee] = (half_t)cv;
            }
        }
    }
    __syncthreads();

    // ---- l=7: 2 nodes; writes h_bf/c_ws for solo ----
    {
        f32x4 acc[5] = {};
#pragma unroll
        for (int kk = 0; kk < 8; ++kk) {
            bf16x8 a0 = *(const bf16x8*)((const char*)A7 + swz(lr * 512 + kk * 64 + lc * 16));
#pragma unroll
            for (int g = 0; g < 5; ++g)
                acc[g] = __builtin_amdgcn_mfma_f32_16x16x32_bf16(a0,
                          *(const bf16x8*)(Wp + g * HH * H2 + kk * 32), acc[g], 0, 0, 0);
        }
#pragma unroll
        for (int r = 0; r < 4; ++r) {
            int j = lc * 4 + r;
            if (j < 2) {
                int node = b * 2 + j;
                int tree = node >> 7;
                int loc  = 127 + (node & 127);
                int base = tree * NPT + loc;
                int o    = base * HH + ee;
                float cl = (float)C8[(2 * j) * HH + ee];
                float cr = (float)C8[(2 * j + 1) * HH + ee];
                float hv, cv;
                GATES5(acc[0][r] + bi, acc[1][r] + bo, acc[2][r] + bu,
                       acc[3][r] + bl, acc[4][r] + br, cl, cr, hv, cv);
                h_g[o]  = hv;
                c_ws[o] = (half_t)cv;
                h_bf[o] = f2bf(hv);
            }
        }
    }
}

// ---------------- solo tail l=6..0 (R22 exact) ----------------
__global__ __launch_bounds__(TPB, 2) void solo_k(
    const float* __restrict__ b_iou, const float* __restrict__ b_f,
    float* __restrict__ h_g, half_t* __restrict__ c_ws,
    const unsigned short* __restrict__ h_bf)
{
    __shared__ __align__(16) unsigned char hb[49152];

    const int tid = threadIdx.x;
    const int w = tid >> 6, lr = tid & 15, lc = (tid & 63) >> 4;
    const int ee = w * 16 + lr;
    const int tb = blockIdx.x * NPT;
    const float bi = b_iou[ee], bo = b_iou[HH + ee], bu = b_iou[2 * HH + ee];
    const float bl = b_f[ee],   br = b_f[HH + ee];

    bf16x8 Bf[5][8];
    const unsigned short* Wp = Wb_g + ee * H2 + lc * 8;
#pragma unroll
    for (int g = 0; g < 5; ++g)
#pragma unroll
        for (int kk = 0; kk < 8; ++kk)
            Bf[g][kk] = *(const bf16x8*)(Wp + g * HH * H2 + kk * 32);

    // ---- stage l=7 h: 128 rows x 256B = 32 KB (rows tb+127 .. tb+254) ----
#pragma unroll
    for (int it = 0; it < 4; ++it) {
        int p = tid + TPB * it;            // 2048 chunks of 16B
        int cc = p >> 4, q = p & 15;
        uint4 v = *(const uint4*)(h_bf + (tb + 127 + cc) * HH + q * 8);
        *(uint4*)(hb + swz(p * 16)) = v;
    }
    __syncthreads();

    // ---- l=6: 64 nodes = two 32-node tiles; children h from LDS, c from global ----
#pragma unroll 1
    for (int tt = 0; tt < 2; ++tt) {
        f32x4 acc[2][5] = {};
#pragma unroll
        for (int kk = 0; kk < 8; ++kk) {
            bf16x8 a0 = *(const bf16x8*)(hb + swz(tt * 16384 + lr * 512 + kk * 64 + lc * 16));
            bf16x8 a1 = *(const bf16x8*)(hb + swz(tt * 16384 + (16 + lr) * 512 + kk * 64 + lc * 16));
#pragma unroll
            for (int g = 0; g < 5; ++g) {
                acc[0][g] = __builtin_amdgcn_mfma_f32_16x16x32_bf16(a0, Bf[g][kk], acc[0][g], 0, 0, 0);
                acc[1][g] = __builtin_amdgcn_mfma_f32_16x16x32_bf16(a1, Bf[g][kk], acc[1][g], 0, 0, 0);
            }
        }
#pragma unroll
        for (int mt = 0; mt < 2; ++mt)
#pragma unroll
            for (int r = 0; r < 4; ++r) {
                int j    = tt * 32 + mt * 16 + lc * 4 + r;   // l=6 node 0..63
                int row  = tb + 63 + j;
                int lrow = tb + 127 + 2 * j;
                float cl = (float)c_ws[lrow * HH + ee];
                float cr = (float)c_ws[lrow * HH + HH + ee];
                float hv, cv;
                GATES5(acc[mt][0][r] + bi, acc[mt][1][r] + bo, acc[mt][2][r] + bu,
                       acc[mt][3][r] + bl, acc[mt][4][r] + br, cl, cr, hv, cv);
                h_g[row * HH + ee]  = hv;
                c_ws[row * HH + ee] = (half_t)cv;
                *(unsigned short*)(hb + 32768 + swz(j * 256 + ee * 2)) = f2bf(hv);
            }
    }

    // ---- l=5..0: ping-pong (l=5 reads the 32K l=6-out region) ----
#pragma unroll 1
    for (int l = 5; l >= 0; --l) {
        const int nl     = 1 << l;
        const int loc0   = nl - 1;
        const int cloc0  = 2 * nl - 1;
        const int cbase  = (l == 5) ? 32768 : ((l & 1) ? 16384 : 0);
        const int obase  = (l == 5) ? 0 : (((l & 1) ? 16384 : 0) ^ 16384);
        const bool mt1   = (nl > 16);

        __syncthreads();

        f32x4 acc[2][5] = {};
#pragma unroll
        for (int kk = 0; kk < 8; ++kk) {
            bf16x8 a0 = *(const bf16x8*)(hb + cbase + swz(lr * 512 + kk * 64 + lc * 16));
#pragma unroll
            for (int g = 0; g < 5; ++g)
                acc[0][g] = __builtin_amdgcn_mfma_f32_16x16x32_bf16(a0, Bf[g][kk], acc[0][g], 0, 0, 0);
            if (mt1) {
                bf16x8 a1 = *(const bf16x8*)(hb + cbase + swz((16 + lr) * 512 + kk * 64 + lc * 16));
#pragma unroll
                for (int g = 0; g < 5; ++g)
                    acc[1][g] = __builtin_amdgcn_mfma_f32_16x16x32_bf16(a1, Bf[g][kk], acc[1][g], 0, 0, 0);
            }
        }
        __syncthreads();

#pragma unroll
        for (int mt = 0; mt < 2; ++mt)
#pragma unroll
            for (int r = 0; r < 4; ++r) {
                int j = mt * 16 + lc * 4 + r;
                if (j >= nl) continue;
                int row  = tb + loc0 + j;
                int lrow = tb + cloc0 + 2 * j;
                float cl = (float)c_ws[lrow * HH + ee];
                float cr = (float)c_ws[lrow * HH + HH + ee];
                float hv, cv;
                GATES5(acc[mt][0][r] + bi, acc[mt][1][r] + bo, acc[mt][2][r] + bu,
                       acc[mt][3][r] + bl, acc[mt][4][r] + br, cl, cr, hv, cv);
                h_g[row * HH + ee]  = hv;
                c_ws[row * HH + ee] = (half_t)cv;
                *(unsigned short*)(hb + obase + swz(j * 256 + ee * 2)) = f2bf(hv);
            }
    }
}

extern "C" void kernel_launch(void* const* d_in, const int* in_sizes, int n_in,
                              void* d_out, int out_size, void* d_ws, size_t ws_size,
                              hipStream_t stream)
{
    const float* iou   = (const float*)d_in[0];
    const float* c_in  = (const float*)d_in[2];
    const float* W_iou = (const float*)d_in[3];
    const float* b_iou = (const float*)d_in[4];
    const float* W_f   = (const float*)d_in[5];
    const float* b_f   = (const float*)d_in[6];
    float* h_out = (float*)d_out;
    half_t* c_ws = (half_t*)d_ws;                                                       // 67 MiB f16 c
    unsigned short* h_bf = (unsigned short*)((char*)d_ws + (size_t)72 * 1024 * 1024);   // 67 MiB bf16 h

    conv_k<<<160, 256, 0, stream>>>(W_iou, W_f);
    leaf14_k<<<2048, TPB, 0, stream>>>(iou, c_in, b_iou, b_f, h_out, c_ws, h_bf);   // leaves + l=14
    level_k<<<1024, TPB, 0, stream>>>(13, b_iou, b_f, h_out, c_ws, h_bf);           // l=13
    level_k<<< 512, TPB, 0, stream>>>(12, b_iou, b_f, h_out, c_ws, h_bf);           // l=12
    quint_k<<<256, TPB, 0, stream>>>(b_iou, b_f, h_out, c_ws, h_bf);                // l=11..7
    solo_k<<<4, TPB, 0, stream>>>(b_iou, b_f, h_out, c_ws, h_bf);                   // l=6..0
}